// Round 1
// baseline (401.236 us; speedup 1.0000x reference)
//
#include <hip/hip_runtime.h>

#define N_NODES 50000
#define N_EDGES 800000
#define HID 64
#define LAYERS 4
#define EP_CAP 2048        // staged srcS capacity per 64-node block (mean ~1024, sigma ~32)

typedef unsigned short u16;
typedef __attribute__((ext_vector_type(8))) __bf16 bf16x8;
typedef __attribute__((ext_vector_type(8))) unsigned short u16x8;
typedef __attribute__((ext_vector_type(4))) float f32x4;

__device__ __forceinline__ u16 f2bf(float f) {
  unsigned u = __builtin_bit_cast(unsigned, f);
  u += 0x7fffu + ((u >> 16) & 1u);   // RNE
  return (u16)(u >> 16);
}
__device__ __forceinline__ float bf2f(u16 s) {
  return __builtin_bit_cast(float, ((unsigned)s) << 16);
}

// ---------------- init: zero cnt + weight prep + encoder (one launch) --------
// W1abT: [L][128][64] bf16 — cols 0-63 = W1a (src), 64-127 = W1b (dst), [n][k]
// Wvx:   [L][3][64] f32  (We@W1c folded rank-3 edge_vec term)
// b1x:   [L][64] f32     (b1 + be@W1c)
// NB1T:  [L][64][128] bf16 — node GEMM1 B: k<64 = M1a^T, k>=64 = (W2@M1b)^T
// bb2:   [L][64] f32     (b2@M1b — scaled by deg in node epilogue)
// M2T:   [L][64][64] bf16
__global__ __launch_bounds__(256) void init_kernel(
    const float* __restrict__ nf, const float* __restrict__ enc_w,
    const float* __restrict__ enc_b,
    const float* __restrict__ ew1, const float* __restrict__ eb1,
    const float* __restrict__ ew2, const float* __restrict__ eb2,
    const float* __restrict__ nw1, const float* __restrict__ nw2,
    const float* __restrict__ edge_enc_w, const float* __restrict__ edge_enc_b,
    u16* __restrict__ h, u16* W1abT, float* Wvx, float* b1x,
    u16* NB1T, float* bb2, u16* M2T, int* __restrict__ cnt) {
  const int T = gridDim.x * 256;
  int tid = blockIdx.x * 256 + threadIdx.x;
  for (int i = tid; i < N_NODES; i += T) cnt[i] = 0;
  {
    const int szA = LAYERS * 128 * 64, szV = LAYERS * 3 * 64, szB = LAYERS * 64;
    const int szN = LAYERS * 64 * 128, szb2 = LAYERS * 64, szM = LAYERS * 64 * 64;
    const int tot = szA + szV + szB + szN + szb2 + szM;
    for (int i = tid; i < tot; i += T) {
      int idx = i;
      if (idx < szA) {
        int l = idx / (128 * 64); int r = idx % (128 * 64);
        int nfc = r / 64; int k = r % 64;
        int half = nfc >> 6, f = nfc & 63;
        W1abT[idx] = f2bf(ew1[(l * 192 + half * 64 + k) * 64 + f]);
        continue;
      }
      idx -= szA;
      if (idx < szV) {
        int l = idx / 192, r = idx % 192, a = r / 64, f = r % 64;
        float s = 0.f;
        for (int m = 0; m < 64; ++m) s += edge_enc_w[a * 64 + m] * ew1[(l * 192 + 128 + m) * 64 + f];
        Wvx[idx] = s;
        continue;
      }
      idx -= szV;
      if (idx < szB) {
        int l = idx / 64, f = idx % 64;
        float s = eb1[l * 64 + f];
        for (int m = 0; m < 64; ++m) s += edge_enc_b[m] * ew1[(l * 192 + 128 + m) * 64 + f];
        b1x[idx] = s;
        continue;
      }
      idx -= szB;
      if (idx < szN) {
        int l = idx / 8192, r = idx % 8192, f = r / 128, k = r % 128;
        float v;
        if (k < 64) v = nw1[(l * 128 + k) * 64 + f];
        else {
          int j = k - 64; float s = 0.f;
          for (int g = 0; g < 64; ++g)
            s += ew2[(l * 64 + j) * 64 + g] * nw1[(l * 128 + 64 + g) * 64 + f];
          v = s;
        }
        NB1T[idx] = f2bf(v);
        continue;
      }
      idx -= szN;
      if (idx < szb2) {
        int l = idx / 64, f = idx % 64;
        float s = 0.f;
        for (int g = 0; g < 64; ++g) s += eb2[l * 64 + g] * nw1[(l * 128 + 64 + g) * 64 + f];
        bb2[idx] = s;
        continue;
      }
      idx -= szb2;
      int l = idx / 4096, r = idx % 4096, f = r / 64, k = r % 64;
      M2T[idx] = f2bf(nw2[(l * 64 + k) * 64 + f]);
    }
  }
  // encoder, vectorized 8 features / thread, 16B stores
  for (int i = tid; i < N_NODES * 8; i += T) {
    int n = i >> 3, j0 = (i & 7) * 8;
    float x0 = nf[n * 3 + 0], x1 = nf[n * 3 + 1], x2 = nf[n * 3 + 2];
    u16x8 v;
#pragma unroll
    for (int j = 0; j < 8; ++j) {
      int jj = j0 + j;
      float s = enc_b[jj] + x0 * enc_w[jj] + x1 * enc_w[64 + jj] + x2 * enc_w[128 + jj];
      v[j] = f2bf(s);
    }
    *(u16x8*)(h + (size_t)n * 64 + j0) = v;
  }
}

// ---------------- CSR build: hist (+rank), scan, atomic-free scatter ---------
__global__ __launch_bounds__(256) void hist_kernel(const int* __restrict__ dstA,
                                                   int* __restrict__ cnt,
                                                   int* __restrict__ rank) {
  int idx = blockIdx.x * 256 + threadIdx.x;
  if (idx < N_EDGES) rank[idx] = atomicAdd(&cnt[dstA[idx]], 1);
}

#define SCAN_NBLK 25
__global__ __launch_bounds__(256) void scan1_kernel(const int* __restrict__ cnt,
                                                    int* __restrict__ offs,
                                                    int* __restrict__ partials) {
  __shared__ int sm[2048];
  __shared__ int ws2[256];
  int t = threadIdx.x, b = blockIdx.x;
  int base = b * 2048;
#pragma unroll
  for (int i = 0; i < 8; ++i) {
    int idx = base + i * 256 + t;
    sm[i * 256 + t] = (idx < N_NODES) ? cnt[idx] : 0;
  }
  __syncthreads();
  int loc[8]; int s = 0;
#pragma unroll
  for (int i = 0; i < 8; ++i) { loc[i] = s; s += sm[t * 8 + i]; }
  ws2[t] = s;
  __syncthreads();
  for (int off = 1; off < 256; off <<= 1) {
    int u = (t >= off) ? ws2[t - off] : 0;
    __syncthreads();
    ws2[t] += u;
    __syncthreads();
  }
  int tbase = (t > 0) ? ws2[t - 1] : 0;
  if (t == 255) partials[b] = ws2[255];   // raw block total
#pragma unroll
  for (int i = 0; i < 8; ++i) {
    int idx = base + t * 8 + i;
    if (idx < N_NODES) offs[idx] = tbase + loc[i];
  }
}

__global__ __launch_bounds__(256) void scan3_kernel(int* __restrict__ offs,
                                                    const int* __restrict__ partials) {
  __shared__ int pref;
  int blk = (blockIdx.x * 256) >> 11;
  if (threadIdx.x == 0) {
    int s = 0;
    for (int i = 0; i < blk; ++i) s += partials[i];
    pref = s;
  }
  __syncthreads();
  int idx = blockIdx.x * 256 + threadIdx.x;
  if (idx < N_NODES) offs[idx] += pref;
}

// atomic-free scatter; stores src*64 (premultiplied element offset)
__global__ __launch_bounds__(256) void scatter_kernel(const int* __restrict__ ei,
                                                      const int* __restrict__ offs,
                                                      const int* __restrict__ rank,
                                                      int* __restrict__ srcS64) {
  int idx = blockIdx.x * 256 + threadIdx.x;
  if (idx >= N_EDGES) return;
  int s = ei[idx], d = ei[N_EDGES + idx];
  srcS64[offs[d] + rank[idx]] = s << 6;
}

// ---------------- su (layer 0 only): S' = h@W1a − pos·Wv ; U' = h@W1b + pos·Wv + b1
__global__ __launch_bounds__(256) void su_kernel(const u16* __restrict__ h,
                                                 const u16* __restrict__ W1abT,
                                                 const float* __restrict__ Wvx,
                                                 const float* __restrict__ b1x,
                                                 const float* __restrict__ pos,
                                                 u16* __restrict__ Sarr,
                                                 u16* __restrict__ Uarr, int layer) {
  __shared__ float sPos[192];
  int t = threadIdx.x;
  int lane = t & 63, wvi = t >> 6;
  int n16 = lane & 15, quad = lane >> 4;
  int n0 = blockIdx.x * 64;
  if (t < 192) {
    int idx = n0 * 3 + t;
    sPos[t] = (idx < N_NODES * 3) ? pos[idx] : 0.f;
  }
  __syncthreads();

  bf16x8 B[2][2];
  float w0[2], w1[2], w2[2], bb[2]; bool isU[2];
#pragma unroll
  for (int nt = 0; nt < 2; ++nt) {
    int col = wvi * 32 + nt * 16 + n16;
    const u16* p = W1abT + (size_t)(layer * 128 + col) * 64 + quad * 8;
    B[nt][0] = __builtin_bit_cast(bf16x8, *(const u16x8*)(p));
    B[nt][1] = __builtin_bit_cast(bf16x8, *(const u16x8*)(p + 32));
    int f = col & 63; isU[nt] = col >= 64;
    w0[nt] = Wvx[(layer * 3 + 0) * 64 + f];
    w1[nt] = Wvx[(layer * 3 + 1) * 64 + f];
    w2[nt] = Wvx[(layer * 3 + 2) * 64 + f];
    bb[nt] = b1x[layer * 64 + f];
  }
  f32x4 acc[4][2];
#pragma unroll
  for (int m = 0; m < 4; ++m)
#pragma unroll
    for (int nt = 0; nt < 2; ++nt) acc[m][nt] = (f32x4){0.f, 0.f, 0.f, 0.f};

#pragma unroll
  for (int m = 0; m < 4; ++m) {
    int row = n0 + m * 16 + n16;
    if (row >= N_NODES) row = N_NODES - 1;
    const u16* hp = h + (size_t)row * 64 + quad * 8;
    bf16x8 a0 = __builtin_bit_cast(bf16x8, *(const u16x8*)(hp));
    bf16x8 a1 = __builtin_bit_cast(bf16x8, *(const u16x8*)(hp + 32));
#pragma unroll
    for (int nt = 0; nt < 2; ++nt) {
      acc[m][nt] = __builtin_amdgcn_mfma_f32_16x16x32_bf16(a0, B[nt][0], acc[m][nt], 0, 0, 0);
      acc[m][nt] = __builtin_amdgcn_mfma_f32_16x16x32_bf16(a1, B[nt][1], acc[m][nt], 0, 0, 0);
    }
  }
#pragma unroll
  for (int m = 0; m < 4; ++m)
#pragma unroll
    for (int nt = 0; nt < 2; ++nt) {
      int col = wvi * 32 + nt * 16 + n16;
      int f = col & 63;
#pragma unroll
      for (int r = 0; r < 4; ++r) {
        int e = m * 16 + quad * 4 + r;
        int grow = n0 + e;
        if (grow < N_NODES) {
          float P = sPos[e * 3] * w0[nt] + sPos[e * 3 + 1] * w1[nt] + sPos[e * 3 + 2] * w2[nt];
          if (!isU[nt]) Sarr[(size_t)grow * 64 + f] = f2bf(acc[m][nt][r] - P);
          else          Uarr[(size_t)grow * 64 + f] = f2bf(acc[m][nt][r] + P + bb[nt]);
        }
      }
    }
}

// ---------------- fused layer kernel: ep aggregation (LDS) + node MLP --------
// ep phase: each wave owns 16 dst nodes; lane = (feature-pair c, edge-half).
// One global_load_dword covers 2 edges (lanes 0-31: edge 2k, 32-63: edge 2k+1).
// agg lands in LDS (stride-72 to dodge bank conflicts) and feeds GEMM1 directly.
// S/U for the NEXT layer are written to the ping-pong buffers (Sw/Uw) — other
// blocks still gather from Sr/Ur, so no cross-block race.
__global__ __launch_bounds__(256) void node_kernel(
    const u16* __restrict__ h, const int* __restrict__ srcS64,
    const int* __restrict__ offs,
    const u16* __restrict__ NB1T, const float* __restrict__ nb1,
    const float* __restrict__ bb2,
    const u16* __restrict__ M2T, const float* __restrict__ nb2,
    u16* __restrict__ h2, int layer,
    const u16* __restrict__ W1abT, const float* __restrict__ Wvx,
    const float* __restrict__ b1x, const float* __restrict__ pos,
    const u16* __restrict__ Sr, const u16* __restrict__ Ur,
    u16* __restrict__ Sw, u16* __restrict__ Uw,
    const float* __restrict__ dec_w, const float* __restrict__ dec_b,
    float* __restrict__ out) {
  __shared__ u16 Hs[64 * 72];
  __shared__ u16 aggT[64 * 72];
  __shared__ int sIdx[EP_CAP];
  __shared__ int sOff[65];
  __shared__ float sDeg[64];
  __shared__ float sPos[192];
  __shared__ float sRed[64][4];
  int t = threadIdx.x;
  int lane = t & 63, wvi = t >> 6;
  int n16 = lane & 15, quad = lane >> 4;
  int F = wvi * 16;
  int n0 = blockIdx.x * 64;

  if (t <= 64) {
    int d = n0 + t;
    sOff[t] = (d < N_NODES) ? offs[d] : N_EDGES;
  }
  __syncthreads();
  if (t < 64) sDeg[t] = (float)(sOff[t + 1] - sOff[t]);
  if (t >= 64 && t < 256) {
    int i = t - 64;
    int idx = n0 * 3 + i;
    sPos[i] = (idx < N_NODES * 3) ? pos[idx] : 0.f;
  }
  int eS = sOff[0];
  int nE = sOff[64] - eS;
  bool fit = (nE <= EP_CAP);
  if (fit) {
    for (int i = t; i < nE; i += 256) sIdx[i] = srcS64[eS + i];
  }
  __syncthreads();

  // ---- ep phase ----
  {
    int c = lane & 31, half = lane >> 5;
    size_t cb = (size_t)(c << 2);
    const char* Sb = (const char*)Sr;
    for (int nl = 0; nl < 16; ++nl) {
      int ln = wvi * 16 + nl;
      int d = n0 + ln;
      int dU = (d < N_NODES) ? d : (N_NODES - 1);
      int e0 = sOff[ln];
      int deg = sOff[ln + 1] - e0;
      unsigned ub2 = *(const unsigned*)((const char*)Ur + (size_t)dU * 128 + cb);
      float ua = bf2f((u16)(ub2 & 0xffffu));
      float ub = bf2f((u16)(ub2 >> 16));
      float suma = 0.f, sumb = 0.f;
      int rel = e0 - eS;
      int pf = (deg >> 1) & ~7;     // pairs in full 8-pair (16-edge) batches
      if (fit) {
        for (int base = 0; base < pf; base += 8) {
          unsigned w[8];
#pragma unroll
          for (int k = 0; k < 8; ++k) {
            int s64 = sIdx[rel + 2 * (base + k) + half];
            w[k] = *(const unsigned*)(Sb + ((size_t)s64 << 1) + cb);
          }
#pragma unroll
          for (int k = 0; k < 8; ++k) {
            suma += fmaxf(bf2f((u16)(w[k] & 0xffffu)) + ua, 0.f);
            sumb += fmaxf(bf2f((u16)(w[k] >> 16)) + ub, 0.f);
          }
        }
        if (2 * pf < deg) {
          unsigned w[8]; bool ok[8];
#pragma unroll
          for (int k = 0; k < 8; ++k) {
            int j = 2 * (pf + k) + half;
            ok[k] = j < deg;
            int s64 = sIdx[rel + (ok[k] ? j : 0)];
            w[k] = *(const unsigned*)(Sb + ((size_t)s64 << 1) + cb);
          }
#pragma unroll
          for (int k = 0; k < 8; ++k) {
            float za = fmaxf(bf2f((u16)(w[k] & 0xffffu)) + ua, 0.f);
            float zb = fmaxf(bf2f((u16)(w[k] >> 16)) + ub, 0.f);
            suma += ok[k] ? za : 0.f;
            sumb += ok[k] ? zb : 0.f;
          }
        }
      } else {   // overflow fallback (cap is ~32 sigma out)
        for (int base = 0; base < pf; base += 8) {
          unsigned w[8];
#pragma unroll
          for (int k = 0; k < 8; ++k) {
            int s64 = srcS64[e0 + 2 * (base + k) + half];
            w[k] = *(const unsigned*)(Sb + ((size_t)s64 << 1) + cb);
          }
#pragma unroll
          for (int k = 0; k < 8; ++k) {
            suma += fmaxf(bf2f((u16)(w[k] & 0xffffu)) + ua, 0.f);
            sumb += fmaxf(bf2f((u16)(w[k] >> 16)) + ub, 0.f);
          }
        }
        if (2 * pf < deg) {
          unsigned w[8]; bool ok[8];
#pragma unroll
          for (int k = 0; k < 8; ++k) {
            int j = 2 * (pf + k) + half;
            ok[k] = j < deg;
            int s64 = srcS64[e0 + (ok[k] ? j : 0)];
            w[k] = *(const unsigned*)(Sb + ((size_t)s64 << 1) + cb);
          }
#pragma unroll
          for (int k = 0; k < 8; ++k) {
            float za = fmaxf(bf2f((u16)(w[k] & 0xffffu)) + ua, 0.f);
            float zb = fmaxf(bf2f((u16)(w[k] >> 16)) + ub, 0.f);
            suma += ok[k] ? za : 0.f;
            sumb += ok[k] ? zb : 0.f;
          }
        }
      }
      suma += __shfl_xor(suma, 32);
      sumb += __shfl_xor(sumb, 32);
      if (half == 0) {
        unsigned pk = (unsigned)f2bf(suma) | ((unsigned)f2bf(sumb) << 16);
        *(unsigned*)((char*)aggT + (size_t)ln * 144 + cb) = pk;
      }
    }
  }
  __syncthreads();

  // ---- GEMM1: [h | agg(LDS)] @ NB1T ----
  bf16x8 B1[4], B2[2];
  {
    const u16* p = NB1T + (size_t)(layer * 64 + F + n16) * 128 + quad * 8;
#pragma unroll
    for (int ks = 0; ks < 4; ++ks) B1[ks] = __builtin_bit_cast(bf16x8, *(const u16x8*)(p + ks * 32));
    const u16* q = M2T + (size_t)(layer * 64 + F + n16) * 64 + quad * 8;
#pragma unroll
    for (int ks = 0; ks < 2; ++ks) B2[ks] = __builtin_bit_cast(bf16x8, *(const u16x8*)(q + ks * 32));
  }
  float bias1 = nb1[layer * 64 + F + n16];
  float bb2f = bb2[layer * 64 + F + n16];
  float bias2 = nb2[layer * 64 + F + n16];

  f32x4 acc[4];
#pragma unroll
  for (int m = 0; m < 4; ++m) acc[m] = (f32x4){0.f, 0.f, 0.f, 0.f};
#pragma unroll
  for (int m = 0; m < 4; ++m) {
    int row = n0 + m * 16 + n16;
    if (row >= N_NODES) row = N_NODES - 1;
    const u16* hp = h + (size_t)row * 64 + quad * 8;
    const u16* ap = aggT + (m * 16 + n16) * 72 + quad * 8;
    bf16x8 a0 = __builtin_bit_cast(bf16x8, *(const u16x8*)(hp));
    bf16x8 a1 = __builtin_bit_cast(bf16x8, *(const u16x8*)(hp + 32));
    bf16x8 a2 = __builtin_bit_cast(bf16x8, *(const u16x8*)(ap));
    bf16x8 a3 = __builtin_bit_cast(bf16x8, *(const u16x8*)(ap + 32));
    acc[m] = __builtin_amdgcn_mfma_f32_16x16x32_bf16(a0, B1[0], acc[m], 0, 0, 0);
    acc[m] = __builtin_amdgcn_mfma_f32_16x16x32_bf16(a1, B1[1], acc[m], 0, 0, 0);
    acc[m] = __builtin_amdgcn_mfma_f32_16x16x32_bf16(a2, B1[2], acc[m], 0, 0, 0);
    acc[m] = __builtin_amdgcn_mfma_f32_16x16x32_bf16(a3, B1[3], acc[m], 0, 0, 0);
  }
#pragma unroll
  for (int m = 0; m < 4; ++m)
#pragma unroll
    for (int r = 0; r < 4; ++r) {
      int e = m * 16 + quad * 4 + r;
      float v = acc[m][r] + bias1 + sDeg[e] * bb2f;
      v = v > 0.f ? v : 0.f;
      Hs[e * 72 + F + n16] = f2bf(v);
    }
  __syncthreads();

  // ---- GEMM2: hidden @ M2T -> h2 (registers) ----
  float c2[4][4];
#pragma unroll
  for (int m = 0; m < 4; ++m) {
    const u16* hp = Hs + (m * 16 + n16) * 72 + quad * 8;
    f32x4 c = (f32x4){0.f, 0.f, 0.f, 0.f};
#pragma unroll
    for (int ks = 0; ks < 2; ++ks) {
      bf16x8 a = __builtin_bit_cast(bf16x8, *(const u16x8*)(hp + ks * 32));
      c = __builtin_amdgcn_mfma_f32_16x16x32_bf16(a, B2[ks], c, 0, 0, 0);
    }
#pragma unroll
    for (int r = 0; r < 4; ++r) c2[m][r] = c[r] + bias2;
  }
  __syncthreads();   // all Hs reads done

  // h2 tile -> LDS; global store only if another layer follows
#pragma unroll
  for (int m = 0; m < 4; ++m)
#pragma unroll
    for (int r = 0; r < 4; ++r) {
      int e = m * 16 + quad * 4 + r;
      u16 hv = f2bf(c2[m][r]);
      Hs[e * 72 + F + n16] = hv;
      int gn = n0 + e;
      if (layer < LAYERS - 1 && gn < N_NODES)
        h2[(size_t)gn * 64 + F + n16] = hv;
    }
  __syncthreads();

  if (layer < LAYERS - 1) {
    int lp = layer + 1;
    bf16x8 B3[2][2];
    float w0[2], w1[2], w2[2], bb[2]; bool isU[2];
#pragma unroll
    for (int nt = 0; nt < 2; ++nt) {
      int col = wvi * 32 + nt * 16 + n16;
      const u16* p = W1abT + (size_t)(lp * 128 + col) * 64 + quad * 8;
      B3[nt][0] = __builtin_bit_cast(bf16x8, *(const u16x8*)(p));
      B3[nt][1] = __builtin_bit_cast(bf16x8, *(const u16x8*)(p + 32));
      int f = col & 63; isU[nt] = col >= 64;
      w0[nt] = Wvx[(lp * 3 + 0) * 64 + f];
      w1[nt] = Wvx[(lp * 3 + 1) * 64 + f];
      w2[nt] = Wvx[(lp * 3 + 2) * 64 + f];
      bb[nt] = b1x[lp * 64 + f];
    }
    f32x4 a3[4][2];
#pragma unroll
    for (int m = 0; m < 4; ++m)
#pragma unroll
      for (int nt = 0; nt < 2; ++nt) a3[m][nt] = (f32x4){0.f, 0.f, 0.f, 0.f};
#pragma unroll
    for (int m = 0; m < 4; ++m) {
      const u16* hp = Hs + (m * 16 + n16) * 72 + quad * 8;
      bf16x8 a0 = __builtin_bit_cast(bf16x8, *(const u16x8*)(hp));
      bf16x8 a1 = __builtin_bit_cast(bf16x8, *(const u16x8*)(hp + 32));
#pragma unroll
      for (int nt = 0; nt < 2; ++nt) {
        a3[m][nt] = __builtin_amdgcn_mfma_f32_16x16x32_bf16(a0, B3[nt][0], a3[m][nt], 0, 0, 0);
        a3[m][nt] = __builtin_amdgcn_mfma_f32_16x16x32_bf16(a1, B3[nt][1], a3[m][nt], 0, 0, 0);
      }
    }
#pragma unroll
    for (int m = 0; m < 4; ++m)
#pragma unroll
      for (int nt = 0; nt < 2; ++nt) {
        int col = wvi * 32 + nt * 16 + n16;
        int f = col & 63;
#pragma unroll
        for (int r = 0; r < 4; ++r) {
          int e = m * 16 + quad * 4 + r;
          int grow = n0 + e;
          if (grow < N_NODES) {
            float P = sPos[e * 3] * w0[nt] + sPos[e * 3 + 1] * w1[nt] + sPos[e * 3 + 2] * w2[nt];
            if (!isU[nt]) Sw[(size_t)grow * 64 + f] = f2bf(a3[m][nt][r] - P);
            else          Uw[(size_t)grow * 64 + f] = f2bf(a3[m][nt][r] + P + bb[nt]);
          }
        }
      }
  } else {
    // fused decoder: out = h2 @ dec_w + dec_b
    int e = t >> 2, part = t & 3;
    float s = 0.f;
#pragma unroll
    for (int j = 0; j < 16; ++j)
      s += bf2f(Hs[e * 72 + part * 16 + j]) * dec_w[part * 16 + j];
    sRed[e][part] = s;
    __syncthreads();
    if (part == 0) {
      int gn = n0 + e;
      if (gn < N_NODES)
        out[gn] = sRed[e][0] + sRed[e][1] + sRed[e][2] + sRed[e][3] + dec_b[0];
    }
  }
}

extern "C" void kernel_launch(void* const* d_in, const int* in_sizes, int n_in,
                              void* d_out, int out_size, void* d_ws, size_t ws_size,
                              hipStream_t stream) {
  const float* node_pos   = (const float*)d_in[0];
  const float* node_feat  = (const float*)d_in[1];
  const int*   edge_index = (const int*)d_in[2];
  const float* enc_w      = (const float*)d_in[3];
  const float* enc_b      = (const float*)d_in[4];
  const float* edge_enc_w = (const float*)d_in[5];
  const float* edge_enc_b = (const float*)d_in[6];
  const float* ew1        = (const float*)d_in[7];
  const float* eb1        = (const float*)d_in[8];
  const float* ew2        = (const float*)d_in[9];
  const float* eb2        = (const float*)d_in[10];
  const float* nw1        = (const float*)d_in[11];
  const float* nb1        = (const float*)d_in[12];
  const float* nw2        = (const float*)d_in[13];
  const float* nb2        = (const float*)d_in[14];
  const float* dec_w      = (const float*)d_in[15];
  const float* dec_b      = (const float*)d_in[16];
  float* out = (float*)d_out;

  char* ws = (char*)d_ws;
  size_t off = 0;
  u16*    hA    = (u16*)(ws + off);    off += (size_t)N_NODES * 64 * 2;
  u16*    hB    = (u16*)(ws + off);    off += (size_t)N_NODES * 64 * 2;
  u16*    Sarr0 = (u16*)(ws + off);    off += (size_t)N_NODES * 64 * 2;
  u16*    Uarr0 = (u16*)(ws + off);    off += (size_t)N_NODES * 64 * 2;
  u16*    Sarr1 = (u16*)(ws + off);    off += (size_t)N_NODES * 64 * 2;
  u16*    Uarr1 = (u16*)(ws + off);    off += (size_t)N_NODES * 64 * 2;
  u16*    W1abT = (u16*)(ws + off);    off += (size_t)LAYERS * 128 * 64 * 2;
  float*  Wvx   = (float*)(ws + off);  off += (size_t)LAYERS * 3 * 64 * 4;
  float*  b1x   = (float*)(ws + off);  off += (size_t)LAYERS * 64 * 4;
  u16*    NB1T  = (u16*)(ws + off);    off += (size_t)LAYERS * 64 * 128 * 2;
  float*  bb2   = (float*)(ws + off);  off += (size_t)LAYERS * 64 * 4;
  u16*    M2T   = (u16*)(ws + off);    off += (size_t)LAYERS * 64 * 64 * 2;
  int*    cnt      = (int*)(ws + off); off += (size_t)N_NODES * 4;
  int*    offsB    = (int*)(ws + off); off += (size_t)N_NODES * 4;
  int*    partials = (int*)(ws + off); off += 32 * 4;
  int*    rank     = (int*)(ws + off); off += (size_t)N_EDGES * 4;
  int*    srcS64   = (int*)(ws + off); off += (size_t)N_EDGES * 4;

  const int* dstA = edge_index + N_EDGES;
  const int NBLK = (N_NODES + 63) / 64;          // 782

  init_kernel<<<1024, 256, 0, stream>>>(
      node_feat, enc_w, enc_b, ew1, eb1, ew2, eb2, nw1, nw2,
      edge_enc_w, edge_enc_b, hA, W1abT, Wvx, b1x, NB1T, bb2, M2T, cnt);

  // one-time CSR build (counting sort by dst, atomic-free scatter)
  hist_kernel<<<(N_EDGES + 255) / 256, 256, 0, stream>>>(dstA, cnt, rank);
  scan1_kernel<<<SCAN_NBLK, 256, 0, stream>>>(cnt, offsB, partials);
  scan3_kernel<<<(N_NODES + 255) / 256, 256, 0, stream>>>(offsB, partials);
  scatter_kernel<<<(N_EDGES + 255) / 256, 256, 0, stream>>>(edge_index, offsB, rank, srcS64);

  su_kernel<<<NBLK, 256, 0, stream>>>(hA, W1abT, Wvx, b1x, node_pos, Sarr0, Uarr0, 0);

  u16* hcur = hA; u16* hnext = hB;
  u16* Sr = Sarr0; u16* Ur = Uarr0; u16* Sw = Sarr1; u16* Uw = Uarr1;
  for (int l = 0; l < LAYERS; ++l) {
    node_kernel<<<NBLK, 256, 0, stream>>>(hcur, srcS64, offsB, NB1T, nb1, bb2, M2T, nb2,
                                          hnext, l, W1abT, Wvx, b1x, node_pos,
                                          Sr, Ur, Sw, Uw, dec_w, dec_b, out);
    u16* tmp;
    tmp = hcur; hcur = hnext; hnext = tmp;
    tmp = Sr; Sr = Sw; Sw = tmp;
    tmp = Ur; Ur = Uw; Uw = tmp;
  }
}

// Round 2
// 356.425 us; speedup vs baseline: 1.1257x; 1.1257x over previous
//
#include <hip/hip_runtime.h>

#define N_NODES 50000
#define N_EDGES 800000
#define HID 64
#define LAYERS 4
#define EP_NPB 32          // dst nodes per ep block (4 waves x 8)
#define EP_CAP 2048        // staged srcS capacity (avg block load ~512)

typedef unsigned short u16;
typedef __attribute__((ext_vector_type(8))) __bf16 bf16x8;
typedef __attribute__((ext_vector_type(8))) unsigned short u16x8;
typedef __attribute__((ext_vector_type(4))) float f32x4;

__device__ __forceinline__ u16 f2bf(float f) {
  unsigned u = __builtin_bit_cast(unsigned, f);
  u += 0x7fffu + ((u >> 16) & 1u);   // RNE
  return (u16)(u >> 16);
}
__device__ __forceinline__ float bf2f(u16 s) {
  return __builtin_bit_cast(float, ((unsigned)s) << 16);
}

// ---------------- init: zero cnt + weight prep + encoder (one launch) --------
// W1abT: [L][128][64] bf16 — cols 0-63 = W1a (src), 64-127 = W1b (dst), [n][k]
// Wvx:   [L][3][64] f32  (We@W1c folded rank-3 edge_vec term)
// b1x:   [L][64] f32     (b1 + be@W1c)
// NB1T:  [L][64][128] bf16 — node GEMM1 B: k<64 = M1a^T, k>=64 = (W2@M1b)^T
// bb2:   [L][64] f32     (b2@M1b — scaled by deg in node epilogue)
// M2T:   [L][64][64] bf16
__global__ __launch_bounds__(256) void init_kernel(
    const float* __restrict__ nf, const float* __restrict__ enc_w,
    const float* __restrict__ enc_b,
    const float* __restrict__ ew1, const float* __restrict__ eb1,
    const float* __restrict__ ew2, const float* __restrict__ eb2,
    const float* __restrict__ nw1, const float* __restrict__ nw2,
    const float* __restrict__ edge_enc_w, const float* __restrict__ edge_enc_b,
    u16* __restrict__ h, u16* W1abT, float* Wvx, float* b1x,
    u16* NB1T, float* bb2, u16* M2T, int* __restrict__ cnt) {
  const int T = gridDim.x * 256;
  int tid = blockIdx.x * 256 + threadIdx.x;
  for (int i = tid; i < N_NODES; i += T) cnt[i] = 0;
  {
    const int szA = LAYERS * 128 * 64, szV = LAYERS * 3 * 64, szB = LAYERS * 64;
    const int szN = LAYERS * 64 * 128, szb2 = LAYERS * 64, szM = LAYERS * 64 * 64;
    const int tot = szA + szV + szB + szN + szb2 + szM;
    for (int i = tid; i < tot; i += T) {
      int idx = i;
      if (idx < szA) {
        int l = idx / (128 * 64); int r = idx % (128 * 64);
        int nfc = r / 64; int k = r % 64;
        int half = nfc >> 6, f = nfc & 63;
        W1abT[idx] = f2bf(ew1[(l * 192 + half * 64 + k) * 64 + f]);
        continue;
      }
      idx -= szA;
      if (idx < szV) {
        int l = idx / 192, r = idx % 192, a = r / 64, f = r % 64;
        float s = 0.f;
        for (int m = 0; m < 64; ++m) s += edge_enc_w[a * 64 + m] * ew1[(l * 192 + 128 + m) * 64 + f];
        Wvx[idx] = s;
        continue;
      }
      idx -= szV;
      if (idx < szB) {
        int l = idx / 64, f = idx % 64;
        float s = eb1[l * 64 + f];
        for (int m = 0; m < 64; ++m) s += edge_enc_b[m] * ew1[(l * 192 + 128 + m) * 64 + f];
        b1x[idx] = s;
        continue;
      }
      idx -= szB;
      if (idx < szN) {
        int l = idx / 8192, r = idx % 8192, f = r / 128, k = r % 128;
        float v;
        if (k < 64) v = nw1[(l * 128 + k) * 64 + f];
        else {
          int j = k - 64; float s = 0.f;
          for (int g = 0; g < 64; ++g)
            s += ew2[(l * 64 + j) * 64 + g] * nw1[(l * 128 + 64 + g) * 64 + f];
          v = s;
        }
        NB1T[idx] = f2bf(v);
        continue;
      }
      idx -= szN;
      if (idx < szb2) {
        int l = idx / 64, f = idx % 64;
        float s = 0.f;
        for (int g = 0; g < 64; ++g) s += eb2[l * 64 + g] * nw1[(l * 128 + 64 + g) * 64 + f];
        bb2[idx] = s;
        continue;
      }
      idx -= szb2;
      int l = idx / 4096, r = idx % 4096, f = r / 64, k = r % 64;
      M2T[idx] = f2bf(nw2[(l * 64 + k) * 64 + f]);
    }
  }
  // encoder, vectorized 8 features / thread, 16B stores
  for (int i = tid; i < N_NODES * 8; i += T) {
    int n = i >> 3, j0 = (i & 7) * 8;
    float x0 = nf[n * 3 + 0], x1 = nf[n * 3 + 1], x2 = nf[n * 3 + 2];
    u16x8 v;
#pragma unroll
    for (int j = 0; j < 8; ++j) {
      int jj = j0 + j;
      float s = enc_b[jj] + x0 * enc_w[jj] + x1 * enc_w[64 + jj] + x2 * enc_w[128 + jj];
      v[j] = f2bf(s);
    }
    *(u16x8*)(h + (size_t)n * 64 + j0) = v;
  }
}

// ---------------- CSR build: hist (+rank), scan, atomic-free scatter ---------
__global__ __launch_bounds__(256) void hist_kernel(const int* __restrict__ dstA,
                                                   int* __restrict__ cnt,
                                                   int* __restrict__ rank) {
  int idx = blockIdx.x * 256 + threadIdx.x;
  if (idx < N_EDGES) rank[idx] = atomicAdd(&cnt[dstA[idx]], 1);
}

#define SCAN_NBLK 25
__global__ __launch_bounds__(256) void scan1_kernel(const int* __restrict__ cnt,
                                                    int* __restrict__ offs,
                                                    int* __restrict__ partials) {
  __shared__ int sm[2048];
  __shared__ int ws2[256];
  int t = threadIdx.x, b = blockIdx.x;
  int base = b * 2048;
#pragma unroll
  for (int i = 0; i < 8; ++i) {
    int idx = base + i * 256 + t;
    sm[i * 256 + t] = (idx < N_NODES) ? cnt[idx] : 0;
  }
  __syncthreads();
  int loc[8]; int s = 0;
#pragma unroll
  for (int i = 0; i < 8; ++i) { loc[i] = s; s += sm[t * 8 + i]; }
  ws2[t] = s;
  __syncthreads();
  for (int off = 1; off < 256; off <<= 1) {
    int u = (t >= off) ? ws2[t - off] : 0;
    __syncthreads();
    ws2[t] += u;
    __syncthreads();
  }
  int tbase = (t > 0) ? ws2[t - 1] : 0;
  if (t == 255) partials[b] = ws2[255];   // raw block total
#pragma unroll
  for (int i = 0; i < 8; ++i) {
    int idx = base + t * 8 + i;
    if (idx < N_NODES) offs[idx] = tbase + loc[i];
  }
}

__global__ __launch_bounds__(256) void scan3_kernel(int* __restrict__ offs,
                                                    const int* __restrict__ partials) {
  __shared__ int pref;
  int blk = (blockIdx.x * 256) >> 11;
  if (threadIdx.x == 0) {
    int s = 0;
    for (int i = 0; i < blk; ++i) s += partials[i];
    pref = s;
  }
  __syncthreads();
  int idx = blockIdx.x * 256 + threadIdx.x;
  if (idx < N_NODES) offs[idx] += pref;
}

// atomic-free scatter; stores src*128 (premultiplied BYTE offset into S rows)
__global__ __launch_bounds__(256) void scatter_kernel(const int* __restrict__ ei,
                                                      const int* __restrict__ offs,
                                                      const int* __restrict__ rank,
                                                      int* __restrict__ srcB) {
  int idx = blockIdx.x * 256 + threadIdx.x;
  if (idx >= N_EDGES) return;
  int s = ei[idx], d = ei[N_EDGES + idx];
  srcB[offs[d] + rank[idx]] = s << 7;
}

// ---------------- su (layer 0 only): S' = h@W1a − pos·Wv ; U' = h@W1b + pos·Wv + b1
__global__ __launch_bounds__(256) void su_kernel(const u16* __restrict__ h,
                                                 const u16* __restrict__ W1abT,
                                                 const float* __restrict__ Wvx,
                                                 const float* __restrict__ b1x,
                                                 const float* __restrict__ pos,
                                                 u16* __restrict__ Sarr,
                                                 u16* __restrict__ Uarr, int layer) {
  __shared__ float sPos[192];
  int t = threadIdx.x;
  int lane = t & 63, wvi = t >> 6;
  int n16 = lane & 15, quad = lane >> 4;
  int n0 = blockIdx.x * 64;
  if (t < 192) {
    int idx = n0 * 3 + t;
    sPos[t] = (idx < N_NODES * 3) ? pos[idx] : 0.f;
  }
  __syncthreads();

  bf16x8 B[2][2];
  float w0[2], w1[2], w2[2], bb[2]; bool isU[2];
#pragma unroll
  for (int nt = 0; nt < 2; ++nt) {
    int col = wvi * 32 + nt * 16 + n16;
    const u16* p = W1abT + (size_t)(layer * 128 + col) * 64 + quad * 8;
    B[nt][0] = __builtin_bit_cast(bf16x8, *(const u16x8*)(p));
    B[nt][1] = __builtin_bit_cast(bf16x8, *(const u16x8*)(p + 32));
    int f = col & 63; isU[nt] = col >= 64;
    w0[nt] = Wvx[(layer * 3 + 0) * 64 + f];
    w1[nt] = Wvx[(layer * 3 + 1) * 64 + f];
    w2[nt] = Wvx[(layer * 3 + 2) * 64 + f];
    bb[nt] = b1x[layer * 64 + f];
  }
  f32x4 acc[4][2];
#pragma unroll
  for (int m = 0; m < 4; ++m)
#pragma unroll
    for (int nt = 0; nt < 2; ++nt) acc[m][nt] = (f32x4){0.f, 0.f, 0.f, 0.f};

#pragma unroll
  for (int m = 0; m < 4; ++m) {
    int row = n0 + m * 16 + n16;
    if (row >= N_NODES) row = N_NODES - 1;
    const u16* hp = h + (size_t)row * 64 + quad * 8;
    bf16x8 a0 = __builtin_bit_cast(bf16x8, *(const u16x8*)(hp));
    bf16x8 a1 = __builtin_bit_cast(bf16x8, *(const u16x8*)(hp + 32));
#pragma unroll
    for (int nt = 0; nt < 2; ++nt) {
      acc[m][nt] = __builtin_amdgcn_mfma_f32_16x16x32_bf16(a0, B[nt][0], acc[m][nt], 0, 0, 0);
      acc[m][nt] = __builtin_amdgcn_mfma_f32_16x16x32_bf16(a1, B[nt][1], acc[m][nt], 0, 0, 0);
    }
  }
#pragma unroll
  for (int m = 0; m < 4; ++m)
#pragma unroll
    for (int nt = 0; nt < 2; ++nt) {
      int col = wvi * 32 + nt * 16 + n16;
      int f = col & 63;
#pragma unroll
      for (int r = 0; r < 4; ++r) {
        int e = m * 16 + quad * 4 + r;
        int grow = n0 + e;
        if (grow < N_NODES) {
          float P = sPos[e * 3] * w0[nt] + sPos[e * 3 + 1] * w1[nt] + sPos[e * 3 + 2] * w2[nt];
          if (!isU[nt]) Sarr[(size_t)grow * 64 + f] = f2bf(acc[m][nt][r] - P);
          else          Uarr[(size_t)grow * 64 + f] = f2bf(acc[m][nt][r] + P + bb[nt]);
        }
      }
    }
}

// ---------------- edge pass: aggH[d] = sum_e relu(S'[src] + U'[d]) -----------
// Standalone (high-occupancy) version with:
//  - paired-edge u32 gathers: lane = (feature-pair c, edge-half); one dword
//    covers 2 features x 1 edge; lanes 0-31 = even edges, 32-63 = odd.
//  - two dst nodes interleaved per inner loop: 16 independent loads in flight.
//  - srcB holds premultiplied byte offsets (src*128).
__global__ __launch_bounds__(256) void ep_kernel(const u16* __restrict__ Sarr,
                                                 const u16* __restrict__ Uarr,
                                                 const int* __restrict__ srcB,
                                                 const int* __restrict__ offs,
                                                 u16* __restrict__ aggH) {
  __shared__ int sIdx[EP_CAP];
  __shared__ int sOff[EP_NPB + 1];
  int t = threadIdx.x;
  int lane = t & 63, wvi = t >> 6;
  int c = lane & 31, half = lane >> 5;
  size_t cb = (size_t)(c << 2);
  int d0b = blockIdx.x * EP_NPB;
  if (t <= EP_NPB) {
    int d = d0b + t;
    sOff[t] = (d < N_NODES) ? offs[d] : N_EDGES;
  }
  __syncthreads();
  int eS = sOff[0];
  int nE = sOff[EP_NPB] - eS;
  bool fit = (nE <= EP_CAP);
  if (fit) {
    for (int i = t; i < nE; i += 256) sIdx[i] = srcB[eS + i];
    if (t == 0 && nE < EP_CAP) sIdx[nE] = 0;   // safe pad for deg-0 tail nodes
  }
  __syncthreads();

  const char* Sb = (const char*)Sarr;
  const char* Ub = (const char*)Uarr;
  for (int i = 0; i < 8; i += 2) {
    int lnA = wvi * 8 + i, lnB = lnA + 1;
    int dA = d0b + lnA, dB = d0b + lnB;
    int e0A = sOff[lnA], degA = sOff[lnA + 1] - e0A;
    int e0B = sOff[lnB], degB = sOff[lnB + 1] - e0B;
    int dAc = dA < N_NODES ? dA : N_NODES - 1;
    int dBc = dB < N_NODES ? dB : N_NODES - 1;
    unsigned upA = *(const unsigned*)(Ub + (size_t)dAc * 128 + cb);
    unsigned upB = *(const unsigned*)(Ub + (size_t)dBc * 128 + cb);
    float uaA = bf2f((u16)(upA & 0xffffu)), ubA = bf2f((u16)(upA >> 16));
    float uaB = bf2f((u16)(upB & 0xffffu)), ubB = bf2f((u16)(upB >> 16));
    float saA = 0.f, sbA = 0.f, saB = 0.f, sbB = 0.f;
    // clamp index bases so deg-0 / out-of-range nodes read a valid staged slot
    int relA = (degA > 0) ? (e0A - eS) : 0;
    int relB = (degB > 0) ? (e0B - eS) : 0;
    int g0A = (degA > 0) ? e0A : 0;
    int g0B = (degB > 0) ? e0B : 0;
    int rA = (degA + 15) >> 4, rB = (degB + 15) >> 4;
    int rmax = rA > rB ? rA : rB;
    if (fit) {
      for (int r = 0; r < rmax; ++r) {
        int base = r * 16 + half;
        unsigned wA[8], wB[8]; bool okA[8], okB[8];
#pragma unroll
        for (int k = 0; k < 8; ++k) {
          int j = base + 2 * k;
          okA[k] = j < degA;
          int sA = sIdx[relA + (okA[k] ? j : 0)];
          wA[k] = *(const unsigned*)(Sb + (size_t)(unsigned)sA + cb);
          okB[k] = j < degB;
          int sB = sIdx[relB + (okB[k] ? j : 0)];
          wB[k] = *(const unsigned*)(Sb + (size_t)(unsigned)sB + cb);
        }
#pragma unroll
        for (int k = 0; k < 8; ++k) {
          float zaA = fmaxf(bf2f((u16)(wA[k] & 0xffffu)) + uaA, 0.f);
          float zbA = fmaxf(bf2f((u16)(wA[k] >> 16)) + ubA, 0.f);
          saA += okA[k] ? zaA : 0.f;
          sbA += okA[k] ? zbA : 0.f;
          float zaB = fmaxf(bf2f((u16)(wB[k] & 0xffffu)) + uaB, 0.f);
          float zbB = fmaxf(bf2f((u16)(wB[k] >> 16)) + ubB, 0.f);
          saB += okB[k] ? zaB : 0.f;
          sbB += okB[k] ? zbB : 0.f;
        }
      }
    } else {   // overflow fallback (statistically never: cap is ~65 sigma out)
      for (int r = 0; r < rmax; ++r) {
        int base = r * 16 + half;
        unsigned wA[8], wB[8]; bool okA[8], okB[8];
#pragma unroll
        for (int k = 0; k < 8; ++k) {
          int j = base + 2 * k;
          okA[k] = j < degA;
          int sA = srcB[g0A + (okA[k] ? j : 0)];
          wA[k] = *(const unsigned*)(Sb + (size_t)(unsigned)sA + cb);
          okB[k] = j < degB;
          int sB = srcB[g0B + (okB[k] ? j : 0)];
          wB[k] = *(const unsigned*)(Sb + (size_t)(unsigned)sB + cb);
        }
#pragma unroll
        for (int k = 0; k < 8; ++k) {
          float zaA = fmaxf(bf2f((u16)(wA[k] & 0xffffu)) + uaA, 0.f);
          float zbA = fmaxf(bf2f((u16)(wA[k] >> 16)) + ubA, 0.f);
          saA += okA[k] ? zaA : 0.f;
          sbA += okA[k] ? zbA : 0.f;
          float zaB = fmaxf(bf2f((u16)(wB[k] & 0xffffu)) + uaB, 0.f);
          float zbB = fmaxf(bf2f((u16)(wB[k] >> 16)) + ubB, 0.f);
          saB += okB[k] ? zaB : 0.f;
          sbB += okB[k] ? zbB : 0.f;
        }
      }
    }
    saA += __shfl_xor(saA, 32);  sbA += __shfl_xor(sbA, 32);
    saB += __shfl_xor(saB, 32);  sbB += __shfl_xor(sbB, 32);
    if (half == 0) {
      if (dA < N_NODES) {
        unsigned pk = (unsigned)f2bf(saA) | ((unsigned)f2bf(sbA) << 16);
        *(unsigned*)((char*)aggH + (size_t)dA * 128 + cb) = pk;
      }
      if (dB < N_NODES) {
        unsigned pk = (unsigned)f2bf(saB) | ((unsigned)f2bf(sbB) << 16);
        *(unsigned*)((char*)aggH + (size_t)dB * 128 + cb) = pk;
      }
    }
  }
}

// ---------------- node MLP (+ fused next-layer S'/U' GEMM, + fused decoder) --
__global__ __launch_bounds__(256) void node_kernel(
    const u16* __restrict__ h, const u16* __restrict__ aggH,
    const int* __restrict__ cnt,
    const u16* __restrict__ NB1T, const float* __restrict__ nb1,
    const float* __restrict__ bb2,
    const u16* __restrict__ M2T, const float* __restrict__ nb2,
    u16* __restrict__ h2, int layer,
    const u16* __restrict__ W1abT, const float* __restrict__ Wvx,
    const float* __restrict__ b1x, const float* __restrict__ pos,
    u16* __restrict__ Sarr, u16* __restrict__ Uarr,
    const float* __restrict__ dec_w, const float* __restrict__ dec_b,
    float* __restrict__ out) {
  __shared__ u16 Hs[64 * 72];
  __shared__ float sDeg[64];
  __shared__ float sPos[192];
  __shared__ float sRed[64][4];
  int t = threadIdx.x;
  int lane = t & 63, wvi = t >> 6;
  int n16 = lane & 15, quad = lane >> 4;
  int F = wvi * 16;
  int n0 = blockIdx.x * 64;

  if (t < 64) {
    int gn = n0 + t;
    sDeg[t] = (gn < N_NODES) ? (float)cnt[gn] : 0.f;
  }
  if (t >= 64 && t < 256) {
    int i = t - 64;
    int idx = n0 * 3 + i;
    sPos[i] = (idx < N_NODES * 3) ? pos[idx] : 0.f;
  }

  bf16x8 B1[4], B2[2];
  {
    const u16* p = NB1T + (size_t)(layer * 64 + F + n16) * 128 + quad * 8;
#pragma unroll
    for (int ks = 0; ks < 4; ++ks) B1[ks] = __builtin_bit_cast(bf16x8, *(const u16x8*)(p + ks * 32));
    const u16* q = M2T + (size_t)(layer * 64 + F + n16) * 64 + quad * 8;
#pragma unroll
    for (int ks = 0; ks < 2; ++ks) B2[ks] = __builtin_bit_cast(bf16x8, *(const u16x8*)(q + ks * 32));
  }
  float bias1 = nb1[layer * 64 + F + n16];
  float bb2f = bb2[layer * 64 + F + n16];
  float bias2 = nb2[layer * 64 + F + n16];
  __syncthreads();

  // GEMM1: [h|aggH] @ NB1T
  f32x4 acc[4];
#pragma unroll
  for (int m = 0; m < 4; ++m) acc[m] = (f32x4){0.f, 0.f, 0.f, 0.f};
#pragma unroll
  for (int m = 0; m < 4; ++m) {
    int row = n0 + m * 16 + n16;
    if (row >= N_NODES) row = N_NODES - 1;
    const u16* hp = h + (size_t)row * 64 + quad * 8;
    const u16* ap = aggH + (size_t)row * 64 + quad * 8;
    bf16x8 a0 = __builtin_bit_cast(bf16x8, *(const u16x8*)(hp));
    bf16x8 a1 = __builtin_bit_cast(bf16x8, *(const u16x8*)(hp + 32));
    bf16x8 a2 = __builtin_bit_cast(bf16x8, *(const u16x8*)(ap));
    bf16x8 a3 = __builtin_bit_cast(bf16x8, *(const u16x8*)(ap + 32));
    acc[m] = __builtin_amdgcn_mfma_f32_16x16x32_bf16(a0, B1[0], acc[m], 0, 0, 0);
    acc[m] = __builtin_amdgcn_mfma_f32_16x16x32_bf16(a1, B1[1], acc[m], 0, 0, 0);
    acc[m] = __builtin_amdgcn_mfma_f32_16x16x32_bf16(a2, B1[2], acc[m], 0, 0, 0);
    acc[m] = __builtin_amdgcn_mfma_f32_16x16x32_bf16(a3, B1[3], acc[m], 0, 0, 0);
  }
#pragma unroll
  for (int m = 0; m < 4; ++m)
#pragma unroll
    for (int r = 0; r < 4; ++r) {
      int e = m * 16 + quad * 4 + r;
      float v = acc[m][r] + bias1 + sDeg[e] * bb2f;
      v = v > 0.f ? v : 0.f;
      Hs[e * 72 + F + n16] = f2bf(v);
    }
  __syncthreads();

  // GEMM2: hidden @ M2T -> h2 (registers)
  float c2[4][4];
#pragma unroll
  for (int m = 0; m < 4; ++m) {
    const u16* hp = Hs + (m * 16 + n16) * 72 + quad * 8;
    f32x4 c = (f32x4){0.f, 0.f, 0.f, 0.f};
#pragma unroll
    for (int ks = 0; ks < 2; ++ks) {
      bf16x8 a = __builtin_bit_cast(bf16x8, *(const u16x8*)(hp + ks * 32));
      c = __builtin_amdgcn_mfma_f32_16x16x32_bf16(a, B2[ks], c, 0, 0, 0);
    }
#pragma unroll
    for (int r = 0; r < 4; ++r) c2[m][r] = c[r] + bias2;
  }
  __syncthreads();   // all Hs reads done

  // h2 tile -> LDS; global store only if another layer follows
#pragma unroll
  for (int m = 0; m < 4; ++m)
#pragma unroll
    for (int r = 0; r < 4; ++r) {
      int e = m * 16 + quad * 4 + r;
      u16 hv = f2bf(c2[m][r]);
      Hs[e * 72 + F + n16] = hv;
      int gn = n0 + e;
      if (layer < LAYERS - 1 && gn < N_NODES)
        h2[(size_t)gn * 64 + F + n16] = hv;
    }
  __syncthreads();

  if (layer < LAYERS - 1) {
    int lp = layer + 1;
    bf16x8 B3[2][2];
    float w0[2], w1[2], w2[2], bb[2]; bool isU[2];
#pragma unroll
    for (int nt = 0; nt < 2; ++nt) {
      int col = wvi * 32 + nt * 16 + n16;
      const u16* p = W1abT + (size_t)(lp * 128 + col) * 64 + quad * 8;
      B3[nt][0] = __builtin_bit_cast(bf16x8, *(const u16x8*)(p));
      B3[nt][1] = __builtin_bit_cast(bf16x8, *(const u16x8*)(p + 32));
      int f = col & 63; isU[nt] = col >= 64;
      w0[nt] = Wvx[(lp * 3 + 0) * 64 + f];
      w1[nt] = Wvx[(lp * 3 + 1) * 64 + f];
      w2[nt] = Wvx[(lp * 3 + 2) * 64 + f];
      bb[nt] = b1x[lp * 64 + f];
    }
    f32x4 a3[4][2];
#pragma unroll
    for (int m = 0; m < 4; ++m)
#pragma unroll
      for (int nt = 0; nt < 2; ++nt) a3[m][nt] = (f32x4){0.f, 0.f, 0.f, 0.f};
#pragma unroll
    for (int m = 0; m < 4; ++m) {
      const u16* hp = Hs + (m * 16 + n16) * 72 + quad * 8;
      bf16x8 a0 = __builtin_bit_cast(bf16x8, *(const u16x8*)(hp));
      bf16x8 a1 = __builtin_bit_cast(bf16x8, *(const u16x8*)(hp + 32));
#pragma unroll
      for (int nt = 0; nt < 2; ++nt) {
        a3[m][nt] = __builtin_amdgcn_mfma_f32_16x16x32_bf16(a0, B3[nt][0], a3[m][nt], 0, 0, 0);
        a3[m][nt] = __builtin_amdgcn_mfma_f32_16x16x32_bf16(a1, B3[nt][1], a3[m][nt], 0, 0, 0);
      }
    }
#pragma unroll
    for (int m = 0; m < 4; ++m)
#pragma unroll
      for (int nt = 0; nt < 2; ++nt) {
        int col = wvi * 32 + nt * 16 + n16;
        int f = col & 63;
#pragma unroll
        for (int r = 0; r < 4; ++r) {
          int e = m * 16 + quad * 4 + r;
          int grow = n0 + e;
          if (grow < N_NODES) {
            float P = sPos[e * 3] * w0[nt] + sPos[e * 3 + 1] * w1[nt] + sPos[e * 3 + 2] * w2[nt];
            if (!isU[nt]) Sarr[(size_t)grow * 64 + f] = f2bf(a3[m][nt][r] - P);
            else          Uarr[(size_t)grow * 64 + f] = f2bf(a3[m][nt][r] + P + bb[nt]);
          }
        }
      }
  } else {
    // fused decoder: out = h2 @ dec_w + dec_b
    int e = t >> 2, part = t & 3;
    float s = 0.f;
#pragma unroll
    for (int j = 0; j < 16; ++j)
      s += bf2f(Hs[e * 72 + part * 16 + j]) * dec_w[part * 16 + j];
    sRed[e][part] = s;
    __syncthreads();
    if (part == 0) {
      int gn = n0 + e;
      if (gn < N_NODES)
        out[gn] = sRed[e][0] + sRed[e][1] + sRed[e][2] + sRed[e][3] + dec_b[0];
    }
  }
}

extern "C" void kernel_launch(void* const* d_in, const int* in_sizes, int n_in,
                              void* d_out, int out_size, void* d_ws, size_t ws_size,
                              hipStream_t stream) {
  const float* node_pos   = (const float*)d_in[0];
  const float* node_feat  = (const float*)d_in[1];
  const int*   edge_index = (const int*)d_in[2];
  const float* enc_w      = (const float*)d_in[3];
  const float* enc_b      = (const float*)d_in[4];
  const float* edge_enc_w = (const float*)d_in[5];
  const float* edge_enc_b = (const float*)d_in[6];
  const float* ew1        = (const float*)d_in[7];
  const float* eb1        = (const float*)d_in[8];
  const float* ew2        = (const float*)d_in[9];
  const float* eb2        = (const float*)d_in[10];
  const float* nw1        = (const float*)d_in[11];
  const float* nb1        = (const float*)d_in[12];
  const float* nw2        = (const float*)d_in[13];
  const float* nb2        = (const float*)d_in[14];
  const float* dec_w      = (const float*)d_in[15];
  const float* dec_b      = (const float*)d_in[16];
  float* out = (float*)d_out;

  char* ws = (char*)d_ws;
  size_t off = 0;
  u16*    hA    = (u16*)(ws + off);    off += (size_t)N_NODES * 64 * 2;
  u16*    hB    = (u16*)(ws + off);    off += (size_t)N_NODES * 64 * 2;
  u16*    Sarr  = (u16*)(ws + off);    off += (size_t)N_NODES * 64 * 2;
  u16*    Uarr  = (u16*)(ws + off);    off += (size_t)N_NODES * 64 * 2;
  u16*    aggH  = (u16*)(ws + off);    off += (size_t)N_NODES * 64 * 2;
  u16*    W1abT = (u16*)(ws + off);    off += (size_t)LAYERS * 128 * 64 * 2;
  float*  Wvx   = (float*)(ws + off);  off += (size_t)LAYERS * 3 * 64 * 4;
  float*  b1x   = (float*)(ws + off);  off += (size_t)LAYERS * 64 * 4;
  u16*    NB1T  = (u16*)(ws + off);    off += (size_t)LAYERS * 64 * 128 * 2;
  float*  bb2   = (float*)(ws + off);  off += (size_t)LAYERS * 64 * 4;
  u16*    M2T   = (u16*)(ws + off);    off += (size_t)LAYERS * 64 * 64 * 2;
  int*    cnt      = (int*)(ws + off); off += (size_t)N_NODES * 4;
  int*    offsB    = (int*)(ws + off); off += (size_t)N_NODES * 4;
  int*    partials = (int*)(ws + off); off += 32 * 4;
  int*    rank     = (int*)(ws + off); off += (size_t)N_EDGES * 4;
  int*    srcB     = (int*)(ws + off); off += (size_t)N_EDGES * 4;

  const int* dstA = edge_index + N_EDGES;
  const int NBLK = (N_NODES + 63) / 64;          // 782
  const int EP_GRID = (N_NODES + EP_NPB - 1) / EP_NPB;  // 1563

  init_kernel<<<1024, 256, 0, stream>>>(
      node_feat, enc_w, enc_b, ew1, eb1, ew2, eb2, nw1, nw2,
      edge_enc_w, edge_enc_b, hA, W1abT, Wvx, b1x, NB1T, bb2, M2T, cnt);

  // one-time CSR build (counting sort by dst, atomic-free scatter)
  hist_kernel<<<(N_EDGES + 255) / 256, 256, 0, stream>>>(dstA, cnt, rank);
  scan1_kernel<<<SCAN_NBLK, 256, 0, stream>>>(cnt, offsB, partials);
  scan3_kernel<<<(N_NODES + 255) / 256, 256, 0, stream>>>(offsB, partials);
  scatter_kernel<<<(N_EDGES + 255) / 256, 256, 0, stream>>>(edge_index, offsB, rank, srcB);

  su_kernel<<<NBLK, 256, 0, stream>>>(hA, W1abT, Wvx, b1x, node_pos, Sarr, Uarr, 0);

  u16* hcur = hA; u16* hnext = hB;
  for (int l = 0; l < LAYERS; ++l) {
    ep_kernel<<<EP_GRID, 256, 0, stream>>>(Sarr, Uarr, srcB, offsB, aggH);
    node_kernel<<<NBLK, 256, 0, stream>>>(hcur, aggH, cnt, NB1T, nb1, bb2, M2T, nb2,
                                          hnext, l, W1abT, Wvx, b1x, node_pos,
                                          Sarr, Uarr, dec_w, dec_b, out);
    u16* tmp = hcur; hcur = hnext; hnext = tmp;
  }
}

// Round 3
// 342.220 us; speedup vs baseline: 1.1724x; 1.0415x over previous
//
#include <hip/hip_runtime.h>

#define N_NODES 50000
#define N_EDGES 800000
#define HID 64
#define LAYERS 4
#define EP_NPB 32          // dst nodes per ep block (4 waves x 8)
#define EP_CAP 2048        // staged srcS capacity (avg block load ~512)

typedef unsigned short u16;
typedef __attribute__((ext_vector_type(8))) __bf16 bf16x8;
typedef __attribute__((ext_vector_type(8))) unsigned short u16x8;
typedef __attribute__((ext_vector_type(4))) float f32x4;
typedef _Float16 h2 __attribute__((ext_vector_type(2)));

__device__ __forceinline__ u16 f2bf(float f) {
  unsigned u = __builtin_bit_cast(unsigned, f);
  u += 0x7fffu + ((u >> 16) & 1u);   // RNE
  return (u16)(u >> 16);
}
__device__ __forceinline__ float bf2f(u16 s) {
  return __builtin_bit_cast(float, ((unsigned)s) << 16);
}
__device__ __forceinline__ u16 f2h(float f) {
  return __builtin_bit_cast(u16, (_Float16)f);
}
// packed f16 helpers (ep inner loop)
__device__ __forceinline__ unsigned pkadd(unsigned a, unsigned b) {
  h2 r = __builtin_bit_cast(h2, a) + __builtin_bit_cast(h2, b);
  return __builtin_bit_cast(unsigned, r);
}
__device__ __forceinline__ unsigned pkmax0(unsigned x) {
  unsigned r, z = 0u;
  asm("v_pk_max_f16 %0, %1, %2" : "=v"(r) : "v"(x), "v"(z));
  return r;
}

// ---------------- init: zero cnt + weight prep + encoder (one launch) --------
// W1abT: [L][128][64] bf16 — cols 0-63 = W1a (src), 64-127 = W1b (dst), [n][k]
// Wvx:   [L][3][64] f32  (We@W1c folded rank-3 edge_vec term)
// b1x:   [L][64] f32     (b1 + be@W1c)
// NB1T:  [L][64][128] bf16 — node GEMM1 B: k<64 = M1a^T, k>=64 = (W2@M1b)^T
// bb2:   [L][64] f32     (b2@M1b — scaled by deg in node epilogue)
// M2T:   [L][64][64] bf16
__global__ __launch_bounds__(256) void init_kernel(
    const float* __restrict__ nf, const float* __restrict__ enc_w,
    const float* __restrict__ enc_b,
    const float* __restrict__ ew1, const float* __restrict__ eb1,
    const float* __restrict__ ew2, const float* __restrict__ eb2,
    const float* __restrict__ nw1, const float* __restrict__ nw2,
    const float* __restrict__ edge_enc_w, const float* __restrict__ edge_enc_b,
    u16* __restrict__ h, u16* W1abT, float* Wvx, float* b1x,
    u16* NB1T, float* bb2, u16* M2T, int* __restrict__ cnt) {
  const int T = gridDim.x * 256;
  int tid = blockIdx.x * 256 + threadIdx.x;
  for (int i = tid; i < N_NODES; i += T) cnt[i] = 0;
  {
    const int szA = LAYERS * 128 * 64, szV = LAYERS * 3 * 64, szB = LAYERS * 64;
    const int szN = LAYERS * 64 * 128, szb2 = LAYERS * 64, szM = LAYERS * 64 * 64;
    const int tot = szA + szV + szB + szN + szb2 + szM;
    for (int i = tid; i < tot; i += T) {
      int idx = i;
      if (idx < szA) {
        int l = idx / (128 * 64); int r = idx % (128 * 64);
        int nfc = r / 64; int k = r % 64;
        int half = nfc >> 6, f = nfc & 63;
        W1abT[idx] = f2bf(ew1[(l * 192 + half * 64 + k) * 64 + f]);
        continue;
      }
      idx -= szA;
      if (idx < szV) {
        int l = idx / 192, r = idx % 192, a = r / 64, f = r % 64;
        float s = 0.f;
        for (int m = 0; m < 64; ++m) s += edge_enc_w[a * 64 + m] * ew1[(l * 192 + 128 + m) * 64 + f];
        Wvx[idx] = s;
        continue;
      }
      idx -= szV;
      if (idx < szB) {
        int l = idx / 64, f = idx % 64;
        float s = eb1[l * 64 + f];
        for (int m = 0; m < 64; ++m) s += edge_enc_b[m] * ew1[(l * 192 + 128 + m) * 64 + f];
        b1x[idx] = s;
        continue;
      }
      idx -= szB;
      if (idx < szN) {
        int l = idx / 8192, r = idx % 8192, f = r / 128, k = r % 128;
        float v;
        if (k < 64) v = nw1[(l * 128 + k) * 64 + f];
        else {
          int j = k - 64; float s = 0.f;
          for (int g = 0; g < 64; ++g)
            s += ew2[(l * 64 + j) * 64 + g] * nw1[(l * 128 + 64 + g) * 64 + f];
          v = s;
        }
        NB1T[idx] = f2bf(v);
        continue;
      }
      idx -= szN;
      if (idx < szb2) {
        int l = idx / 64, f = idx % 64;
        float s = 0.f;
        for (int g = 0; g < 64; ++g) s += eb2[l * 64 + g] * nw1[(l * 128 + 64 + g) * 64 + f];
        bb2[idx] = s;
        continue;
      }
      idx -= szb2;
      int l = idx / 4096, r = idx % 4096, f = r / 64, k = r % 64;
      M2T[idx] = f2bf(nw2[(l * 64 + k) * 64 + f]);
    }
  }
  // encoder, vectorized 8 features / thread, 16B stores
  for (int i = tid; i < N_NODES * 8; i += T) {
    int n = i >> 3, j0 = (i & 7) * 8;
    float x0 = nf[n * 3 + 0], x1 = nf[n * 3 + 1], x2 = nf[n * 3 + 2];
    u16x8 v;
#pragma unroll
    for (int j = 0; j < 8; ++j) {
      int jj = j0 + j;
      float s = enc_b[jj] + x0 * enc_w[jj] + x1 * enc_w[64 + jj] + x2 * enc_w[128 + jj];
      v[j] = f2bf(s);
    }
    *(u16x8*)(h + (size_t)n * 64 + j0) = v;
  }
}

// ---------------- CSR build: hist (+rank), scan, atomic-free scatter ---------
__global__ __launch_bounds__(256) void hist_kernel(const int* __restrict__ dstA,
                                                   int* __restrict__ cnt,
                                                   int* __restrict__ rank) {
  int idx = blockIdx.x * 256 + threadIdx.x;
  if (idx < N_EDGES) rank[idx] = atomicAdd(&cnt[dstA[idx]], 1);
}

#define SCAN_NBLK 25
__global__ __launch_bounds__(256) void scan1_kernel(const int* __restrict__ cnt,
                                                    int* __restrict__ offs,
                                                    int* __restrict__ partials) {
  __shared__ int sm[2048];
  __shared__ int ws2[256];
  int t = threadIdx.x, b = blockIdx.x;
  int base = b * 2048;
#pragma unroll
  for (int i = 0; i < 8; ++i) {
    int idx = base + i * 256 + t;
    sm[i * 256 + t] = (idx < N_NODES) ? cnt[idx] : 0;
  }
  __syncthreads();
  int loc[8]; int s = 0;
#pragma unroll
  for (int i = 0; i < 8; ++i) { loc[i] = s; s += sm[t * 8 + i]; }
  ws2[t] = s;
  __syncthreads();
  for (int off = 1; off < 256; off <<= 1) {
    int u = (t >= off) ? ws2[t - off] : 0;
    __syncthreads();
    ws2[t] += u;
    __syncthreads();
  }
  int tbase = (t > 0) ? ws2[t - 1] : 0;
  if (t == 255) partials[b] = ws2[255];   // raw block total
#pragma unroll
  for (int i = 0; i < 8; ++i) {
    int idx = base + t * 8 + i;
    if (idx < N_NODES) offs[idx] = tbase + loc[i];
  }
}

__global__ __launch_bounds__(256) void scan3_kernel(int* __restrict__ offs,
                                                    const int* __restrict__ partials) {
  __shared__ int pref;
  int blk = (blockIdx.x * 256) >> 11;
  if (threadIdx.x == 0) {
    int s = 0;
    for (int i = 0; i < blk; ++i) s += partials[i];
    pref = s;
  }
  __syncthreads();
  int idx = blockIdx.x * 256 + threadIdx.x;
  if (idx < N_NODES) offs[idx] += pref;
}

// atomic-free scatter; stores src*128 (premultiplied BYTE offset into S rows)
__global__ __launch_bounds__(256) void scatter_kernel(const int* __restrict__ ei,
                                                      const int* __restrict__ offs,
                                                      const int* __restrict__ rank,
                                                      int* __restrict__ srcB) {
  int idx = blockIdx.x * 256 + threadIdx.x;
  if (idx >= N_EDGES) return;
  int s = ei[idx], d = ei[N_EDGES + idx];
  srcB[offs[d] + rank[idx]] = s << 7;
}

// ---------------- su (layer 0 only): S' = h@W1a − pos·Wv ; U' = h@W1b + pos·Wv + b1
// S'/U' stored as FP16 (consumed by ep's packed-f16 math)
__global__ __launch_bounds__(256) void su_kernel(const u16* __restrict__ h,
                                                 const u16* __restrict__ W1abT,
                                                 const float* __restrict__ Wvx,
                                                 const float* __restrict__ b1x,
                                                 const float* __restrict__ pos,
                                                 u16* __restrict__ Sarr,
                                                 u16* __restrict__ Uarr, int layer) {
  __shared__ float sPos[192];
  int t = threadIdx.x;
  int lane = t & 63, wvi = t >> 6;
  int n16 = lane & 15, quad = lane >> 4;
  int n0 = blockIdx.x * 64;
  if (t < 192) {
    int idx = n0 * 3 + t;
    sPos[t] = (idx < N_NODES * 3) ? pos[idx] : 0.f;
  }
  __syncthreads();

  bf16x8 B[2][2];
  float w0[2], w1[2], w2[2], bb[2]; bool isU[2];
#pragma unroll
  for (int nt = 0; nt < 2; ++nt) {
    int col = wvi * 32 + nt * 16 + n16;
    const u16* p = W1abT + (size_t)(layer * 128 + col) * 64 + quad * 8;
    B[nt][0] = __builtin_bit_cast(bf16x8, *(const u16x8*)(p));
    B[nt][1] = __builtin_bit_cast(bf16x8, *(const u16x8*)(p + 32));
    int f = col & 63; isU[nt] = col >= 64;
    w0[nt] = Wvx[(layer * 3 + 0) * 64 + f];
    w1[nt] = Wvx[(layer * 3 + 1) * 64 + f];
    w2[nt] = Wvx[(layer * 3 + 2) * 64 + f];
    bb[nt] = b1x[layer * 64 + f];
  }
  f32x4 acc[4][2];
#pragma unroll
  for (int m = 0; m < 4; ++m)
#pragma unroll
    for (int nt = 0; nt < 2; ++nt) acc[m][nt] = (f32x4){0.f, 0.f, 0.f, 0.f};

#pragma unroll
  for (int m = 0; m < 4; ++m) {
    int row = n0 + m * 16 + n16;
    if (row >= N_NODES) row = N_NODES - 1;
    const u16* hp = h + (size_t)row * 64 + quad * 8;
    bf16x8 a0 = __builtin_bit_cast(bf16x8, *(const u16x8*)(hp));
    bf16x8 a1 = __builtin_bit_cast(bf16x8, *(const u16x8*)(hp + 32));
#pragma unroll
    for (int nt = 0; nt < 2; ++nt) {
      acc[m][nt] = __builtin_amdgcn_mfma_f32_16x16x32_bf16(a0, B[nt][0], acc[m][nt], 0, 0, 0);
      acc[m][nt] = __builtin_amdgcn_mfma_f32_16x16x32_bf16(a1, B[nt][1], acc[m][nt], 0, 0, 0);
    }
  }
#pragma unroll
  for (int m = 0; m < 4; ++m)
#pragma unroll
    for (int nt = 0; nt < 2; ++nt) {
      int col = wvi * 32 + nt * 16 + n16;
      int f = col & 63;
#pragma unroll
      for (int r = 0; r < 4; ++r) {
        int e = m * 16 + quad * 4 + r;
        int grow = n0 + e;
        if (grow < N_NODES) {
          float P = sPos[e * 3] * w0[nt] + sPos[e * 3 + 1] * w1[nt] + sPos[e * 3 + 2] * w2[nt];
          if (!isU[nt]) Sarr[(size_t)grow * 64 + f] = f2h(acc[m][nt][r] - P);
          else          Uarr[(size_t)grow * 64 + f] = f2h(acc[m][nt][r] + P + bb[nt]);
        }
      }
    }
}

// ---------------- edge pass: aggH[d] = sum_e relu(S'[src] + U'[d]) -----------
// Packed-f16 inner loop: one u32 load = 2 f16 features of one edge; lane =
// (feature-pair c, edge-half). Per k: pk_add + pk_max + pk_add = 3 VALU for
// 2 edges x 2 features. Packed accumulator bounded to 8 terms per round, then
// folded into f32. Full rounds (both interleaved nodes have 16 valid edges)
// run mask-free.
__global__ __launch_bounds__(256) void ep_kernel(const u16* __restrict__ Sarr,
                                                 const u16* __restrict__ Uarr,
                                                 const int* __restrict__ srcB,
                                                 const int* __restrict__ offs,
                                                 u16* __restrict__ aggH) {
  __shared__ int sIdx[EP_CAP];
  __shared__ int sOff[EP_NPB + 1];
  int t = threadIdx.x;
  int lane = t & 63, wvi = t >> 6;
  int c = lane & 31, half = lane >> 5;
  unsigned cbu = (unsigned)(c << 2);
  int d0b = blockIdx.x * EP_NPB;
  if (t <= EP_NPB) {
    int d = d0b + t;
    sOff[t] = (d < N_NODES) ? offs[d] : N_EDGES;
  }
  __syncthreads();
  int eS = sOff[0];
  int nE = sOff[EP_NPB] - eS;
  bool fit = (nE <= EP_CAP);
  if (fit) {
    for (int i = t; i < nE; i += 256) sIdx[i] = srcB[eS + i];
    if (t == 0 && nE < EP_CAP) sIdx[nE] = 0;   // safe pad for deg-0 tail nodes
  }
  __syncthreads();

  const char* __restrict__ Sb = (const char*)Sarr;
  const char* __restrict__ Ub = (const char*)Uarr;
  for (int i = 0; i < 8; i += 2) {
    int lnA = wvi * 8 + i, lnB = lnA + 1;
    int dA = d0b + lnA, dB = d0b + lnB;
    int e0A = sOff[lnA], degA = sOff[lnA + 1] - e0A;
    int e0B = sOff[lnB], degB = sOff[lnB + 1] - e0B;
    int dAc = dA < N_NODES ? dA : N_NODES - 1;
    int dBc = dB < N_NODES ? dB : N_NODES - 1;
    unsigned upA = *(const unsigned*)(Ub + (size_t)dAc * 128 + cbu);
    unsigned upB = *(const unsigned*)(Ub + (size_t)dBc * 128 + cbu);
    float saA = 0.f, sbA = 0.f, saB = 0.f, sbB = 0.f;
    // clamp index bases so deg-0 / out-of-range nodes read a valid staged slot
    int relA = (degA > 0) ? (e0A - eS) : 0;
    int relB = (degB > 0) ? (e0B - eS) : 0;
    int g0A = (degA > 0) ? e0A : 0;
    int g0B = (degB > 0) ? e0B : 0;
    int degMin = degA < degB ? degA : degB;
    int degMax = degA > degB ? degA : degB;
    int fullr = degMin >> 4;                 // rounds where BOTH nodes are full
    int rmax = (degMax + 15) >> 4;
    if (fit) {
      int r = 0;
      for (; r < fullr; ++r) {               // mask-free path
        int base = r * 16 + half;
        unsigned wA[8], wB[8];
#pragma unroll
        for (int k = 0; k < 8; ++k) {
          int j = base + 2 * k;
          unsigned oA = (unsigned)sIdx[relA + j] + cbu;
          wA[k] = *(const unsigned*)(Sb + oA);
          unsigned oB = (unsigned)sIdx[relB + j] + cbu;
          wB[k] = *(const unsigned*)(Sb + oB);
        }
        unsigned pA = 0u, pB = 0u;
#pragma unroll
        for (int k = 0; k < 8; ++k) {
          pA = pkadd(pA, pkmax0(pkadd(wA[k], upA)));
          pB = pkadd(pB, pkmax0(pkadd(wB[k], upB)));
        }
        h2 hA2 = __builtin_bit_cast(h2, pA);
        h2 hB2 = __builtin_bit_cast(h2, pB);
        saA += (float)hA2[0]; sbA += (float)hA2[1];
        saB += (float)hB2[0]; sbB += (float)hB2[1];
      }
      for (; r < rmax; ++r) {                // masked remainder
        int base = r * 16 + half;
        unsigned wA[8], wB[8]; bool okA[8], okB[8];
#pragma unroll
        for (int k = 0; k < 8; ++k) {
          int j = base + 2 * k;
          okA[k] = j < degA;
          unsigned oA = (unsigned)sIdx[relA + (okA[k] ? j : 0)] + cbu;
          wA[k] = *(const unsigned*)(Sb + oA);
          okB[k] = j < degB;
          unsigned oB = (unsigned)sIdx[relB + (okB[k] ? j : 0)] + cbu;
          wB[k] = *(const unsigned*)(Sb + oB);
        }
        unsigned pA = 0u, pB = 0u;
#pragma unroll
        for (int k = 0; k < 8; ++k) {
          unsigned zA = pkmax0(pkadd(wA[k], upA));
          pA = pkadd(pA, okA[k] ? zA : 0u);
          unsigned zB = pkmax0(pkadd(wB[k], upB));
          pB = pkadd(pB, okB[k] ? zB : 0u);
        }
        h2 hA2 = __builtin_bit_cast(h2, pA);
        h2 hB2 = __builtin_bit_cast(h2, pB);
        saA += (float)hA2[0]; sbA += (float)hA2[1];
        saB += (float)hB2[0]; sbB += (float)hB2[1];
      }
    } else {   // overflow fallback (statistically never: cap is ~65 sigma out)
      for (int r = 0; r < rmax; ++r) {
        int base = r * 16 + half;
        unsigned wA[8], wB[8]; bool okA[8], okB[8];
#pragma unroll
        for (int k = 0; k < 8; ++k) {
          int j = base + 2 * k;
          okA[k] = j < degA;
          unsigned oA = (unsigned)srcB[g0A + (okA[k] ? j : 0)] + cbu;
          wA[k] = *(const unsigned*)(Sb + oA);
          okB[k] = j < degB;
          unsigned oB = (unsigned)srcB[g0B + (okB[k] ? j : 0)] + cbu;
          wB[k] = *(const unsigned*)(Sb + oB);
        }
        unsigned pA = 0u, pB = 0u;
#pragma unroll
        for (int k = 0; k < 8; ++k) {
          unsigned zA = pkmax0(pkadd(wA[k], upA));
          pA = pkadd(pA, okA[k] ? zA : 0u);
          unsigned zB = pkmax0(pkadd(wB[k], upB));
          pB = pkadd(pB, okB[k] ? zB : 0u);
        }
        h2 hA2 = __builtin_bit_cast(h2, pA);
        h2 hB2 = __builtin_bit_cast(h2, pB);
        saA += (float)hA2[0]; sbA += (float)hA2[1];
        saB += (float)hB2[0]; sbB += (float)hB2[1];
      }
    }
    saA += __shfl_xor(saA, 32);  sbA += __shfl_xor(sbA, 32);
    saB += __shfl_xor(saB, 32);  sbB += __shfl_xor(sbB, 32);
    if (half == 0) {
      if (dA < N_NODES) {
        unsigned pk = (unsigned)f2bf(saA) | ((unsigned)f2bf(sbA) << 16);
        *(unsigned*)((char*)aggH + (size_t)dA * 128 + cbu) = pk;
      }
      if (dB < N_NODES) {
        unsigned pk = (unsigned)f2bf(saB) | ((unsigned)f2bf(sbB) << 16);
        *(unsigned*)((char*)aggH + (size_t)dB * 128 + cbu) = pk;
      }
    }
  }
}

// ---------------- node MLP (+ fused next-layer S'/U' GEMM, + fused decoder) --
__global__ __launch_bounds__(256) void node_kernel(
    const u16* __restrict__ h, const u16* __restrict__ aggH,
    const int* __restrict__ cnt,
    const u16* __restrict__ NB1T, const float* __restrict__ nb1,
    const float* __restrict__ bb2,
    const u16* __restrict__ M2T, const float* __restrict__ nb2,
    u16* __restrict__ h2, int layer,
    const u16* __restrict__ W1abT, const float* __restrict__ Wvx,
    const float* __restrict__ b1x, const float* __restrict__ pos,
    u16* __restrict__ Sarr, u16* __restrict__ Uarr,
    const float* __restrict__ dec_w, const float* __restrict__ dec_b,
    float* __restrict__ out) {
  __shared__ u16 Hs[64 * 72];
  __shared__ float sDeg[64];
  __shared__ float sPos[192];
  __shared__ float sRed[64][4];
  int t = threadIdx.x;
  int lane = t & 63, wvi = t >> 6;
  int n16 = lane & 15, quad = lane >> 4;
  int F = wvi * 16;
  int n0 = blockIdx.x * 64;

  if (t < 64) {
    int gn = n0 + t;
    sDeg[t] = (gn < N_NODES) ? (float)cnt[gn] : 0.f;
  }
  if (t >= 64 && t < 256) {
    int i = t - 64;
    int idx = n0 * 3 + i;
    sPos[i] = (idx < N_NODES * 3) ? pos[idx] : 0.f;
  }

  bf16x8 B1[4], B2[2];
  {
    const u16* p = NB1T + (size_t)(layer * 64 + F + n16) * 128 + quad * 8;
#pragma unroll
    for (int ks = 0; ks < 4; ++ks) B1[ks] = __builtin_bit_cast(bf16x8, *(const u16x8*)(p + ks * 32));
    const u16* q = M2T + (size_t)(layer * 64 + F + n16) * 64 + quad * 8;
#pragma unroll
    for (int ks = 0; ks < 2; ++ks) B2[ks] = __builtin_bit_cast(bf16x8, *(const u16x8*)(q + ks * 32));
  }
  float bias1 = nb1[layer * 64 + F + n16];
  float bb2f = bb2[layer * 64 + F + n16];
  float bias2 = nb2[layer * 64 + F + n16];
  __syncthreads();

  // GEMM1: [h|aggH] @ NB1T
  f32x4 acc[4];
#pragma unroll
  for (int m = 0; m < 4; ++m) acc[m] = (f32x4){0.f, 0.f, 0.f, 0.f};
#pragma unroll
  for (int m = 0; m < 4; ++m) {
    int row = n0 + m * 16 + n16;
    if (row >= N_NODES) row = N_NODES - 1;
    const u16* hp = h + (size_t)row * 64 + quad * 8;
    const u16* ap = aggH + (size_t)row * 64 + quad * 8;
    bf16x8 a0 = __builtin_bit_cast(bf16x8, *(const u16x8*)(hp));
    bf16x8 a1 = __builtin_bit_cast(bf16x8, *(const u16x8*)(hp + 32));
    bf16x8 a2 = __builtin_bit_cast(bf16x8, *(const u16x8*)(ap));
    bf16x8 a3 = __builtin_bit_cast(bf16x8, *(const u16x8*)(ap + 32));
    acc[m] = __builtin_amdgcn_mfma_f32_16x16x32_bf16(a0, B1[0], acc[m], 0, 0, 0);
    acc[m] = __builtin_amdgcn_mfma_f32_16x16x32_bf16(a1, B1[1], acc[m], 0, 0, 0);
    acc[m] = __builtin_amdgcn_mfma_f32_16x16x32_bf16(a2, B1[2], acc[m], 0, 0, 0);
    acc[m] = __builtin_amdgcn_mfma_f32_16x16x32_bf16(a3, B1[3], acc[m], 0, 0, 0);
  }
#pragma unroll
  for (int m = 0; m < 4; ++m)
#pragma unroll
    for (int r = 0; r < 4; ++r) {
      int e = m * 16 + quad * 4 + r;
      float v = acc[m][r] + bias1 + sDeg[e] * bb2f;
      v = v > 0.f ? v : 0.f;
      Hs[e * 72 + F + n16] = f2bf(v);
    }
  __syncthreads();

  // GEMM2: hidden @ M2T -> h2 (registers)
  float c2[4][4];
#pragma unroll
  for (int m = 0; m < 4; ++m) {
    const u16* hp = Hs + (m * 16 + n16) * 72 + quad * 8;
    f32x4 c = (f32x4){0.f, 0.f, 0.f, 0.f};
#pragma unroll
    for (int ks = 0; ks < 2; ++ks) {
      bf16x8 a = __builtin_bit_cast(bf16x8, *(const u16x8*)(hp + ks * 32));
      c = __builtin_amdgcn_mfma_f32_16x16x32_bf16(a, B2[ks], c, 0, 0, 0);
    }
#pragma unroll
    for (int r = 0; r < 4; ++r) c2[m][r] = c[r] + bias2;
  }
  __syncthreads();   // all Hs reads done

  // h2 tile -> LDS; global store only if another layer follows
#pragma unroll
  for (int m = 0; m < 4; ++m)
#pragma unroll
    for (int r = 0; r < 4; ++r) {
      int e = m * 16 + quad * 4 + r;
      u16 hv = f2bf(c2[m][r]);
      Hs[e * 72 + F + n16] = hv;
      int gn = n0 + e;
      if (layer < LAYERS - 1 && gn < N_NODES)
        h2[(size_t)gn * 64 + F + n16] = hv;
    }
  __syncthreads();

  if (layer < LAYERS - 1) {
    int lp = layer + 1;
    bf16x8 B3[2][2];
    float w0[2], w1[2], w2[2], bb[2]; bool isU[2];
#pragma unroll
    for (int nt = 0; nt < 2; ++nt) {
      int col = wvi * 32 + nt * 16 + n16;
      const u16* p = W1abT + (size_t)(lp * 128 + col) * 64 + quad * 8;
      B3[nt][0] = __builtin_bit_cast(bf16x8, *(const u16x8*)(p));
      B3[nt][1] = __builtin_bit_cast(bf16x8, *(const u16x8*)(p + 32));
      int f = col & 63; isU[nt] = col >= 64;
      w0[nt] = Wvx[(lp * 3 + 0) * 64 + f];
      w1[nt] = Wvx[(lp * 3 + 1) * 64 + f];
      w2[nt] = Wvx[(lp * 3 + 2) * 64 + f];
      bb[nt] = b1x[lp * 64 + f];
    }
    f32x4 a3[4][2];
#pragma unroll
    for (int m = 0; m < 4; ++m)
#pragma unroll
      for (int nt = 0; nt < 2; ++nt) a3[m][nt] = (f32x4){0.f, 0.f, 0.f, 0.f};
#pragma unroll
    for (int m = 0; m < 4; ++m) {
      const u16* hp = Hs + (m * 16 + n16) * 72 + quad * 8;
      bf16x8 a0 = __builtin_bit_cast(bf16x8, *(const u16x8*)(hp));
      bf16x8 a1 = __builtin_bit_cast(bf16x8, *(const u16x8*)(hp + 32));
#pragma unroll
      for (int nt = 0; nt < 2; ++nt) {
        a3[m][nt] = __builtin_amdgcn_mfma_f32_16x16x32_bf16(a0, B3[nt][0], a3[m][nt], 0, 0, 0);
        a3[m][nt] = __builtin_amdgcn_mfma_f32_16x16x32_bf16(a1, B3[nt][1], a3[m][nt], 0, 0, 0);
      }
    }
#pragma unroll
    for (int m = 0; m < 4; ++m)
#pragma unroll
      for (int nt = 0; nt < 2; ++nt) {
        int col = wvi * 32 + nt * 16 + n16;
        int f = col & 63;
#pragma unroll
        for (int r = 0; r < 4; ++r) {
          int e = m * 16 + quad * 4 + r;
          int grow = n0 + e;
          if (grow < N_NODES) {
            float P = sPos[e * 3] * w0[nt] + sPos[e * 3 + 1] * w1[nt] + sPos[e * 3 + 2] * w2[nt];
            if (!isU[nt]) Sarr[(size_t)grow * 64 + f] = f2h(a3[m][nt][r] - P);
            else          Uarr[(size_t)grow * 64 + f] = f2h(a3[m][nt][r] + P + bb[nt]);
          }
        }
      }
  } else {
    // fused decoder: out = h2 @ dec_w + dec_b
    int e = t >> 2, part = t & 3;
    float s = 0.f;
#pragma unroll
    for (int j = 0; j < 16; ++j)
      s += bf2f(Hs[e * 72 + part * 16 + j]) * dec_w[part * 16 + j];
    sRed[e][part] = s;
    __syncthreads();
    if (part == 0) {
      int gn = n0 + e;
      if (gn < N_NODES)
        out[gn] = sRed[e][0] + sRed[e][1] + sRed[e][2] + sRed[e][3] + dec_b[0];
    }
  }
}

extern "C" void kernel_launch(void* const* d_in, const int* in_sizes, int n_in,
                              void* d_out, int out_size, void* d_ws, size_t ws_size,
                              hipStream_t stream) {
  const float* node_pos   = (const float*)d_in[0];
  const float* node_feat  = (const float*)d_in[1];
  const int*   edge_index = (const int*)d_in[2];
  const float* enc_w      = (const float*)d_in[3];
  const float* enc_b      = (const float*)d_in[4];
  const float* edge_enc_w = (const float*)d_in[5];
  const float* edge_enc_b = (const float*)d_in[6];
  const float* ew1        = (const float*)d_in[7];
  const float* eb1        = (const float*)d_in[8];
  const float* ew2        = (const float*)d_in[9];
  const float* eb2        = (const float*)d_in[10];
  const float* nw1        = (const float*)d_in[11];
  const float* nb1        = (const float*)d_in[12];
  const float* nw2        = (const float*)d_in[13];
  const float* nb2        = (const float*)d_in[14];
  const float* dec_w      = (const float*)d_in[15];
  const float* dec_b      = (const float*)d_in[16];
  float* out = (float*)d_out;

  char* ws = (char*)d_ws;
  size_t off = 0;
  u16*    hA    = (u16*)(ws + off);    off += (size_t)N_NODES * 64 * 2;
  u16*    hB    = (u16*)(ws + off);    off += (size_t)N_NODES * 64 * 2;
  u16*    Sarr  = (u16*)(ws + off);    off += (size_t)N_NODES * 64 * 2;
  u16*    Uarr  = (u16*)(ws + off);    off += (size_t)N_NODES * 64 * 2;
  u16*    aggH  = (u16*)(ws + off);    off += (size_t)N_NODES * 64 * 2;
  u16*    W1abT = (u16*)(ws + off);    off += (size_t)LAYERS * 128 * 64 * 2;
  float*  Wvx   = (float*)(ws + off);  off += (size_t)LAYERS * 3 * 64 * 4;
  float*  b1x   = (float*)(ws + off);  off += (size_t)LAYERS * 64 * 4;
  u16*    NB1T  = (u16*)(ws + off);    off += (size_t)LAYERS * 64 * 128 * 2;
  float*  bb2   = (float*)(ws + off);  off += (size_t)LAYERS * 64 * 4;
  u16*    M2T   = (u16*)(ws + off);    off += (size_t)LAYERS * 64 * 64 * 2;
  int*    cnt      = (int*)(ws + off); off += (size_t)N_NODES * 4;
  int*    offsB    = (int*)(ws + off); off += (size_t)N_NODES * 4;
  int*    partials = (int*)(ws + off); off += 32 * 4;
  int*    rank     = (int*)(ws + off); off += (size_t)N_EDGES * 4;
  int*    srcB     = (int*)(ws + off); off += (size_t)N_EDGES * 4;

  const int* dstA = edge_index + N_EDGES;
  const int NBLK = (N_NODES + 63) / 64;          // 782
  const int EP_GRID = (N_NODES + EP_NPB - 1) / EP_NPB;  // 1563

  init_kernel<<<1024, 256, 0, stream>>>(
      node_feat, enc_w, enc_b, ew1, eb1, ew2, eb2, nw1, nw2,
      edge_enc_w, edge_enc_b, hA, W1abT, Wvx, b1x, NB1T, bb2, M2T, cnt);

  // one-time CSR build (counting sort by dst, atomic-free scatter)
  hist_kernel<<<(N_EDGES + 255) / 256, 256, 0, stream>>>(dstA, cnt, rank);
  scan1_kernel<<<SCAN_NBLK, 256, 0, stream>>>(cnt, offsB, partials);
  scan3_kernel<<<(N_NODES + 255) / 256, 256, 0, stream>>>(offsB, partials);
  scatter_kernel<<<(N_EDGES + 255) / 256, 256, 0, stream>>>(edge_index, offsB, rank, srcB);

  su_kernel<<<NBLK, 256, 0, stream>>>(hA, W1abT, Wvx, b1x, node_pos, Sarr, Uarr, 0);

  u16* hcur = hA; u16* hnext = hB;
  for (int l = 0; l < LAYERS; ++l) {
    ep_kernel<<<EP_GRID, 256, 0, stream>>>(Sarr, Uarr, srcB, offsB, aggH);
    node_kernel<<<NBLK, 256, 0, stream>>>(hcur, aggH, cnt, NB1T, nb1, bb2, M2T, nb2,
                                          hnext, l, W1abT, Wvx, b1x, node_pos,
                                          Sarr, Uarr, dec_w, dec_b, out);
    u16* tmp = hcur; hcur = hnext; hnext = tmp;
  }
}

// Round 5
// 311.958 us; speedup vs baseline: 1.2862x; 1.0970x over previous
//
#include <hip/hip_runtime.h>

#define N_NODES 50000
#define N_EDGES 800000
#define HID 64
#define LAYERS 4
#define EP_CAP 2048        // staged srcS capacity per 32-node tile (avg ~512)
#define SCAN_NBLK 25

typedef unsigned short u16;
typedef __attribute__((ext_vector_type(8))) __bf16 bf16x8;
typedef __attribute__((ext_vector_type(8))) unsigned short u16x8;
typedef __attribute__((ext_vector_type(4))) float f32x4;
typedef _Float16 f16x2 __attribute__((ext_vector_type(2)));

__device__ __forceinline__ u16 f2bf(float f) {
  unsigned u = __builtin_bit_cast(unsigned, f);
  u += 0x7fffu + ((u >> 16) & 1u);   // RNE
  return (u16)(u >> 16);
}
__device__ __forceinline__ float bf2f(u16 s) {
  return __builtin_bit_cast(float, ((unsigned)s) << 16);
}
__device__ __forceinline__ u16 f2h(float f) {
  return __builtin_bit_cast(u16, (_Float16)f);
}
__device__ __forceinline__ unsigned pkadd(unsigned a, unsigned b) {
  f16x2 r = __builtin_bit_cast(f16x2, a) + __builtin_bit_cast(f16x2, b);
  return __builtin_bit_cast(unsigned, r);
}
__device__ __forceinline__ unsigned pkmax0(unsigned x) {
  unsigned r, z = 0u;
  asm("v_pk_max_f16 %0, %1, %2" : "=v"(r) : "v"(x), "v"(z));
  return r;
}

// ---------------- init: zero cnt + weight prep (one launch; encoder moved) ---
// W1abT: [L][128][64] bf16 — cols 0-63 = W1a (src), 64-127 = W1b (dst), [n][k]
// Wvx:   [L][3][64] f32  (We@W1c folded rank-3 edge_vec term)
// b1x:   [L][64] f32     (b1 + be@W1c)
// NB1T:  [L][64][128] bf16 — node GEMM1 B: k<64 = M1a^T, k>=64 = (W2@M1b)^T
// bb2:   [L][64] f32     (b2@M1b — scaled by deg in node epilogue)
// M2T:   [L][64][64] bf16
__global__ __launch_bounds__(256) void init_kernel(
    const float* __restrict__ ew1, const float* __restrict__ eb1,
    const float* __restrict__ ew2, const float* __restrict__ eb2,
    const float* __restrict__ nw1, const float* __restrict__ nw2,
    const float* __restrict__ edge_enc_w, const float* __restrict__ edge_enc_b,
    u16* W1abT, float* Wvx, float* b1x,
    u16* NB1T, float* bb2, u16* M2T, int* __restrict__ cnt) {
  const int T = gridDim.x * 256;
  int tid = blockIdx.x * 256 + threadIdx.x;
  for (int i = tid; i < N_NODES; i += T) cnt[i] = 0;
  const int szA = LAYERS * 128 * 64, szV = LAYERS * 3 * 64, szB = LAYERS * 64;
  const int szN = LAYERS * 64 * 128, szb2 = LAYERS * 64, szM = LAYERS * 64 * 64;
  const int tot = szA + szV + szB + szN + szb2 + szM;
  for (int i = tid; i < tot; i += T) {
    int idx = i;
    if (idx < szA) {
      int l = idx / (128 * 64); int r = idx % (128 * 64);
      int nfc = r / 64; int k = r % 64;
      int half = nfc >> 6, f = nfc & 63;
      W1abT[idx] = f2bf(ew1[(l * 192 + half * 64 + k) * 64 + f]);
      continue;
    }
    idx -= szA;
    if (idx < szV) {
      int l = idx / 192, r = idx % 192, a = r / 64, f = r % 64;
      float s = 0.f;
      for (int m = 0; m < 64; ++m) s += edge_enc_w[a * 64 + m] * ew1[(l * 192 + 128 + m) * 64 + f];
      Wvx[idx] = s;
      continue;
    }
    idx -= szV;
    if (idx < szB) {
      int l = idx / 64, f = idx % 64;
      float s = eb1[l * 64 + f];
      for (int m = 0; m < 64; ++m) s += edge_enc_b[m] * ew1[(l * 192 + 128 + m) * 64 + f];
      b1x[idx] = s;
      continue;
    }
    idx -= szB;
    if (idx < szN) {
      int l = idx / 8192, r = idx % 8192, f = r / 128, k = r % 128;
      float v;
      if (k < 64) v = nw1[(l * 128 + k) * 64 + f];
      else {
        int j = k - 64; float s = 0.f;
        for (int g = 0; g < 64; ++g)
          s += ew2[(l * 64 + j) * 64 + g] * nw1[(l * 128 + 64 + g) * 64 + f];
        v = s;
      }
      NB1T[idx] = f2bf(v);
      continue;
    }
    idx -= szN;
    if (idx < szb2) {
      int l = idx / 64, f = idx % 64;
      float s = 0.f;
      for (int g = 0; g < 64; ++g) s += eb2[l * 64 + g] * nw1[(l * 128 + 64 + g) * 64 + f];
      bb2[idx] = s;
      continue;
    }
    idx -= szb2;
    int l = idx / 4096, r = idx % 4096, f = r / 64, k = r % 64;
    M2T[idx] = f2bf(nw2[(l * 64 + k) * 64 + f]);
  }
}

// ---------------- CSR build: hist (+rank), scan, atomic-free scatter ---------
__global__ __launch_bounds__(256) void hist_kernel(const int* __restrict__ dstA,
                                                   int* __restrict__ cnt,
                                                   int* __restrict__ rank) {
  int idx = blockIdx.x * 256 + threadIdx.x;
  if (idx < N_EDGES) rank[idx] = atomicAdd(&cnt[dstA[idx]], 1);
}

__global__ __launch_bounds__(256) void scan1_kernel(const int* __restrict__ cnt,
                                                    int* __restrict__ offs,
                                                    int* __restrict__ partials) {
  __shared__ int sm[2048];
  __shared__ int ws2[256];
  int t = threadIdx.x, b = blockIdx.x;
  int base = b * 2048;
#pragma unroll
  for (int i = 0; i < 8; ++i) {
    int idx = base + i * 256 + t;
    sm[i * 256 + t] = (idx < N_NODES) ? cnt[idx] : 0;
  }
  __syncthreads();
  int loc[8]; int s = 0;
#pragma unroll
  for (int i = 0; i < 8; ++i) { loc[i] = s; s += sm[t * 8 + i]; }
  ws2[t] = s;
  __syncthreads();
  for (int off = 1; off < 256; off <<= 1) {
    int u = (t >= off) ? ws2[t - off] : 0;
    __syncthreads();
    ws2[t] += u;
    __syncthreads();
  }
  int tbase = (t > 0) ? ws2[t - 1] : 0;
  if (t == 255) partials[b] = ws2[255];
#pragma unroll
  for (int i = 0; i < 8; ++i) {
    int idx = base + t * 8 + i;
    if (idx < N_NODES) offs[idx] = tbase + loc[i];
  }
}

__global__ __launch_bounds__(256) void scan3_kernel(int* __restrict__ offs,
                                                    const int* __restrict__ partials) {
  __shared__ int pref;
  int blk = (blockIdx.x * 256) >> 11;
  if (threadIdx.x == 0) {
    int s = 0;
    for (int i = 0; i < blk; ++i) s += partials[i];
    pref = s;
  }
  __syncthreads();
  int idx = blockIdx.x * 256 + threadIdx.x;
  if (idx < N_NODES) offs[idx] += pref;
}

// atomic-free scatter; stores src*128 (premultiplied BYTE offset into S rows)
__global__ __launch_bounds__(256) void scatter_kernel(const int* __restrict__ ei,
                                                      const int* __restrict__ offs,
                                                      const int* __restrict__ rank,
                                                      int* __restrict__ srcB) {
  int idx = blockIdx.x * 256 + threadIdx.x;
  if (idx >= N_EDGES) return;
  int s = ei[idx], d = ei[N_EDGES + idx];
  srcB[offs[d] + rank[idx]] = s << 7;
}

// ---------------- encsu: encoder tile -> LDS -> su GEMM (layer 0 S'/U') -----
// S' = h@W1a − pos·Wv ; U' = h@W1b + pos·Wv + b1   (f16 storage)
__global__ __launch_bounds__(256) void encsu_kernel(
    const float* __restrict__ nf, const float* __restrict__ enc_w,
    const float* __restrict__ enc_b,
    const u16* __restrict__ W1abT, const float* __restrict__ Wvx,
    const float* __restrict__ b1x, const float* __restrict__ pos,
    u16* __restrict__ h, u16* __restrict__ Sarr, u16* __restrict__ Uarr) {
  __shared__ u16 hT[64 * 72];
  __shared__ float sPos[192];
  __shared__ float sNf[192];
  int t = threadIdx.x;
  int lane = t & 63, wvi = t >> 6;
  int n16 = lane & 15, quad = lane >> 4;
  int n0 = blockIdx.x * 64;
  if (t < 192) {
    int idx = n0 * 3 + t;
    bool ok = idx < N_NODES * 3;
    sPos[t] = ok ? pos[idx] : 0.f;
    sNf[t] = ok ? nf[idx] : 0.f;
  }
  __syncthreads();
  // encoder: thread -> (node n = t>>2, 16-feature group g = t&3)
  {
    int n = t >> 2, g = t & 3;
    float x0 = sNf[n * 3], x1 = sNf[n * 3 + 1], x2 = sNf[n * 3 + 2];
    u16x8 v0, v1;
#pragma unroll
    for (int j = 0; j < 8; ++j) {
      int jj = g * 16 + j;
      v0[j] = f2bf(enc_b[jj] + x0 * enc_w[jj] + x1 * enc_w[64 + jj] + x2 * enc_w[128 + jj]);
      int jj2 = jj + 8;
      v1[j] = f2bf(enc_b[jj2] + x0 * enc_w[jj2] + x1 * enc_w[64 + jj2] + x2 * enc_w[128 + jj2]);
    }
    *(u16x8*)(hT + n * 72 + g * 16) = v0;
    *(u16x8*)(hT + n * 72 + g * 16 + 8) = v1;
    int gn = n0 + n;
    if (gn < N_NODES) {
      *(u16x8*)(h + (size_t)gn * 64 + g * 16) = v0;
      *(u16x8*)(h + (size_t)gn * 64 + g * 16 + 8) = v1;
    }
  }
  __syncthreads();

  bf16x8 B[2][2];
  float w0[2], w1[2], w2[2], bb[2]; bool isU[2];
#pragma unroll
  for (int nt = 0; nt < 2; ++nt) {
    int col = wvi * 32 + nt * 16 + n16;
    const u16* p = W1abT + (size_t)col * 64 + quad * 8;   // layer 0
    B[nt][0] = __builtin_bit_cast(bf16x8, *(const u16x8*)(p));
    B[nt][1] = __builtin_bit_cast(bf16x8, *(const u16x8*)(p + 32));
    int f = col & 63; isU[nt] = col >= 64;
    w0[nt] = Wvx[f];
    w1[nt] = Wvx[64 + f];
    w2[nt] = Wvx[128 + f];
    bb[nt] = b1x[f];
  }
  f32x4 acc[4][2];
#pragma unroll
  for (int m = 0; m < 4; ++m)
#pragma unroll
    for (int nt = 0; nt < 2; ++nt) acc[m][nt] = (f32x4){0.f, 0.f, 0.f, 0.f};
#pragma unroll
  for (int m = 0; m < 4; ++m) {
    const u16* hp = hT + (m * 16 + n16) * 72 + quad * 8;
    bf16x8 a0 = __builtin_bit_cast(bf16x8, *(const u16x8*)(hp));
    bf16x8 a1 = __builtin_bit_cast(bf16x8, *(const u16x8*)(hp + 32));
#pragma unroll
    for (int nt = 0; nt < 2; ++nt) {
      acc[m][nt] = __builtin_amdgcn_mfma_f32_16x16x32_bf16(a0, B[nt][0], acc[m][nt], 0, 0, 0);
      acc[m][nt] = __builtin_amdgcn_mfma_f32_16x16x32_bf16(a1, B[nt][1], acc[m][nt], 0, 0, 0);
    }
  }
#pragma unroll
  for (int m = 0; m < 4; ++m)
#pragma unroll
    for (int nt = 0; nt < 2; ++nt) {
      int col = wvi * 32 + nt * 16 + n16;
      int f = col & 63;
#pragma unroll
      for (int r = 0; r < 4; ++r) {
        int e = m * 16 + quad * 4 + r;
        int grow = n0 + e;
        if (grow < N_NODES) {
          float P = sPos[e * 3] * w0[nt] + sPos[e * 3 + 1] * w1[nt] + sPos[e * 3 + 2] * w2[nt];
          if (!isU[nt]) Sarr[(size_t)grow * 64 + f] = f2h(acc[m][nt][r] - P);
          else          Uarr[(size_t)grow * 64 + f] = f2h(acc[m][nt][r] + P + bb[nt]);
        }
      }
    }
}

// ---------------- fused layer: ep (LDS agg) + node MLP, 32-node tiles -------
// Grid 1563 blocks (~6/CU) so the gather phase has R3-standalone occupancy;
// agg never touches global. Each of 4 waves gathers for 8 dst nodes
// (pair-interleaved packed-f16, R3's proven inner loop), then the block does
// the 32-row node MLP with agg from LDS. S/U ping-pong across launches.
__global__ __launch_bounds__(256) void layer_kernel(
    const u16* __restrict__ h, const int* __restrict__ srcB,
    const int* __restrict__ offs,
    const u16* __restrict__ Sr, const u16* __restrict__ Ur,
    const u16* __restrict__ NB1T, const float* __restrict__ nb1,
    const float* __restrict__ bb2,
    const u16* __restrict__ M2T, const float* __restrict__ nb2,
    u16* __restrict__ hnext, int layer,
    const u16* __restrict__ W1abT, const float* __restrict__ Wvx,
    const float* __restrict__ b1x, const float* __restrict__ pos,
    u16* __restrict__ Sw, u16* __restrict__ Uw,
    const float* __restrict__ dec_w, const float* __restrict__ dec_b,
    float* __restrict__ out) {
  __shared__ int sIdx[EP_CAP];
  __shared__ int sOff[33];
  __shared__ u16 aggT[32 * 72];
  __shared__ u16 Hs[32 * 72];
  __shared__ float sPos[96];
  __shared__ float sRed[32][8];
  int t = threadIdx.x;
  int lane = t & 63, wvi = t >> 6;
  int n16 = lane & 15, quad = lane >> 4;
  int F = wvi * 16;
  int n0 = blockIdx.x * 32;

  if (t <= 32) {
    int d = n0 + t;
    sOff[t] = (d < N_NODES) ? offs[d] : N_EDGES;
  }
  if (t >= 64 && t < 160) {
    int i = t - 64;
    int idx = n0 * 3 + i;
    sPos[i] = (idx < N_NODES * 3) ? pos[idx] : 0.f;
  }
  __syncthreads();
  int eS = sOff[0];
  int nE = sOff[32] - eS;
  bool fit = (nE <= EP_CAP);
  if (fit) {
    for (int i = t; i < nE; i += 256) sIdx[i] = srcB[eS + i];
    if (t == 0 && nE < EP_CAP) sIdx[nE] = 0;   // safe pad for deg-0 nodes
  }
  __syncthreads();

  // ==== ep phase ====
  {
    int c = lane & 31, half = lane >> 5;
    unsigned cbu = (unsigned)(c << 2);
    const char* __restrict__ Sb = (const char*)Sr;
    const char* __restrict__ Ub = (const char*)Ur;
    for (int i = 0; i < 8; i += 2) {
      int lnA = wvi * 8 + i;
      int dA = n0 + lnA;
      int e0A = sOff[lnA], degA = sOff[lnA + 1] - e0A;
      int e0B = sOff[lnA + 1], degB = sOff[lnA + 2] - e0B;
      int dAc = dA < N_NODES ? dA : N_NODES - 1;
      int dBc = (dA + 1) < N_NODES ? (dA + 1) : N_NODES - 1;
      unsigned upA = *(const unsigned*)(Ub + (size_t)dAc * 128 + cbu);
      unsigned upB = *(const unsigned*)(Ub + (size_t)dBc * 128 + cbu);
      float saA = 0.f, sbA = 0.f, saB = 0.f, sbB = 0.f;
      int relA = (degA > 0) ? (e0A - eS) : 0;
      int relB = (degB > 0) ? (e0B - eS) : 0;
      int g0A = (degA > 0) ? e0A : 0;
      int g0B = (degB > 0) ? e0B : 0;
      int degMin = degA < degB ? degA : degB;
      int degMax = degA > degB ? degA : degB;
      int fullr = degMin >> 4;
      int rmax = (degMax + 15) >> 4;
      if (fit) {
        int r = 0;
        for (; r < fullr; ++r) {             // mask-free
          int base = r * 16 + half;
          unsigned wA[8], wB[8];
#pragma unroll
          for (int kk = 0; kk < 8; ++kk) {
            int j = base + 2 * kk;
            wA[kk] = *(const unsigned*)(Sb + (unsigned)sIdx[relA + j] + cbu);
            wB[kk] = *(const unsigned*)(Sb + (unsigned)sIdx[relB + j] + cbu);
          }
          unsigned pA = 0u, pB = 0u;
#pragma unroll
          for (int kk = 0; kk < 8; ++kk) {
            pA = pkadd(pA, pkmax0(pkadd(wA[kk], upA)));
            pB = pkadd(pB, pkmax0(pkadd(wB[kk], upB)));
          }
          f16x2 hA2 = __builtin_bit_cast(f16x2, pA);
          f16x2 hB2 = __builtin_bit_cast(f16x2, pB);
          saA += (float)hA2[0]; sbA += (float)hA2[1];
          saB += (float)hB2[0]; sbB += (float)hB2[1];
        }
        for (; r < rmax; ++r) {              // masked remainder
          int base = r * 16 + half;
          unsigned wA[8], wB[8]; bool okA[8], okB[8];
#pragma unroll
          for (int kk = 0; kk < 8; ++kk) {
            int j = base + 2 * kk;
            okA[kk] = j < degA;
            wA[kk] = *(const unsigned*)(Sb + (unsigned)sIdx[relA + (okA[kk] ? j : 0)] + cbu);
            okB[kk] = j < degB;
            wB[kk] = *(const unsigned*)(Sb + (unsigned)sIdx[relB + (okB[kk] ? j : 0)] + cbu);
          }
          unsigned pA = 0u, pB = 0u;
#pragma unroll
          for (int kk = 0; kk < 8; ++kk) {
            unsigned zA = pkmax0(pkadd(wA[kk], upA));
            pA = pkadd(pA, okA[kk] ? zA : 0u);
            unsigned zB = pkmax0(pkadd(wB[kk], upB));
            pB = pkadd(pB, okB[kk] ? zB : 0u);
          }
          f16x2 hA2 = __builtin_bit_cast(f16x2, pA);
          f16x2 hB2 = __builtin_bit_cast(f16x2, pB);
          saA += (float)hA2[0]; sbA += (float)hA2[1];
          saB += (float)hB2[0]; sbB += (float)hB2[1];
        }
      } else {                                // overflow fallback
        for (int r = 0; r < rmax; ++r) {
          int base = r * 16 + half;
          unsigned wA[8], wB[8]; bool okA[8], okB[8];
#pragma unroll
          for (int kk = 0; kk < 8; ++kk) {
            int j = base + 2 * kk;
            okA[kk] = j < degA;
            wA[kk] = *(const unsigned*)(Sb + (unsigned)srcB[g0A + (okA[kk] ? j : 0)] + cbu);
            okB[kk] = j < degB;
            wB[kk] = *(const unsigned*)(Sb + (unsigned)srcB[g0B + (okB[kk] ? j : 0)] + cbu);
          }
          unsigned pA = 0u, pB = 0u;
#pragma unroll
          for (int kk = 0; kk < 8; ++kk) {
            unsigned zA = pkmax0(pkadd(wA[kk], upA));
            pA = pkadd(pA, okA[kk] ? zA : 0u);
            unsigned zB = pkmax0(pkadd(wB[kk], upB));
            pB = pkadd(pB, okB[kk] ? zB : 0u);
          }
          f16x2 hA2 = __builtin_bit_cast(f16x2, pA);
          f16x2 hB2 = __builtin_bit_cast(f16x2, pB);
          saA += (float)hA2[0]; sbA += (float)hA2[1];
          saB += (float)hB2[0]; sbB += (float)hB2[1];
        }
      }
      saA += __shfl_xor(saA, 32);  sbA += __shfl_xor(sbA, 32);
      saB += __shfl_xor(saB, 32);  sbB += __shfl_xor(sbB, 32);
      if (half == 0) {
        unsigned pk = (unsigned)f2bf(saA) | ((unsigned)f2bf(sbA) << 16);
        *(unsigned*)((char*)aggT + (size_t)lnA * 144 + cbu) = pk;
        unsigned pk2 = (unsigned)f2bf(saB) | ((unsigned)f2bf(sbB) << 16);
        *(unsigned*)((char*)aggT + (size_t)(lnA + 1) * 144 + cbu) = pk2;
      }
    }
  }
  __syncthreads();

  // ==== node MLP ====
  bf16x8 B1[4], B2[2];
  {
    const u16* p = NB1T + (size_t)(layer * 64 + F + n16) * 128 + quad * 8;
#pragma unroll
    for (int ks = 0; ks < 4; ++ks) B1[ks] = __builtin_bit_cast(bf16x8, *(const u16x8*)(p + ks * 32));
    const u16* q = M2T + (size_t)(layer * 64 + F + n16) * 64 + quad * 8;
#pragma unroll
    for (int ks = 0; ks < 2; ++ks) B2[ks] = __builtin_bit_cast(bf16x8, *(const u16x8*)(q + ks * 32));
  }
  float bias1 = nb1[layer * 64 + F + n16];
  float bb2f = bb2[layer * 64 + F + n16];
  float bias2 = nb2[layer * 64 + F + n16];

  // GEMM1: [h | aggT] @ NB1T (32 rows)
  f32x4 acc[2];
#pragma unroll
  for (int m = 0; m < 2; ++m) acc[m] = (f32x4){0.f, 0.f, 0.f, 0.f};
#pragma unroll
  for (int m = 0; m < 2; ++m) {
    int row = n0 + m * 16 + n16;
    if (row >= N_NODES) row = N_NODES - 1;
    const u16* hp = h + (size_t)row * 64 + quad * 8;
    const u16* ap = aggT + (m * 16 + n16) * 72 + quad * 8;
    bf16x8 a0 = __builtin_bit_cast(bf16x8, *(const u16x8*)(hp));
    bf16x8 a1 = __builtin_bit_cast(bf16x8, *(const u16x8*)(hp + 32));
    bf16x8 a2 = __builtin_bit_cast(bf16x8, *(const u16x8*)(ap));
    bf16x8 a3 = __builtin_bit_cast(bf16x8, *(const u16x8*)(ap + 32));
    acc[m] = __builtin_amdgcn_mfma_f32_16x16x32_bf16(a0, B1[0], acc[m], 0, 0, 0);
    acc[m] = __builtin_amdgcn_mfma_f32_16x16x32_bf16(a1, B1[1], acc[m], 0, 0, 0);
    acc[m] = __builtin_amdgcn_mfma_f32_16x16x32_bf16(a2, B1[2], acc[m], 0, 0, 0);
    acc[m] = __builtin_amdgcn_mfma_f32_16x16x32_bf16(a3, B1[3], acc[m], 0, 0, 0);
  }
#pragma unroll
  for (int m = 0; m < 2; ++m)
#pragma unroll
    for (int r = 0; r < 4; ++r) {
      int e = m * 16 + quad * 4 + r;
      float dg = (float)(sOff[e + 1] - sOff[e]);
      float v = acc[m][r] + bias1 + dg * bb2f;
      v = v > 0.f ? v : 0.f;
      Hs[e * 72 + F + n16] = f2bf(v);
    }
  __syncthreads();

  // GEMM2: hidden @ M2T -> h2 (registers)
  float c2[2][4];
#pragma unroll
  for (int m = 0; m < 2; ++m) {
    const u16* hp = Hs + (m * 16 + n16) * 72 + quad * 8;
    f32x4 cc = (f32x4){0.f, 0.f, 0.f, 0.f};
#pragma unroll
    for (int ks = 0; ks < 2; ++ks) {
      bf16x8 a = __builtin_bit_cast(bf16x8, *(const u16x8*)(hp + ks * 32));
      cc = __builtin_amdgcn_mfma_f32_16x16x32_bf16(a, B2[ks], cc, 0, 0, 0);
    }
#pragma unroll
    for (int r = 0; r < 4; ++r) c2[m][r] = cc[r] + bias2;
  }
  __syncthreads();   // all Hs reads done

  // h2 -> LDS (+ global if another layer follows)
#pragma unroll
  for (int m = 0; m < 2; ++m)
#pragma unroll
    for (int r = 0; r < 4; ++r) {
      int e = m * 16 + quad * 4 + r;
      u16 hv = f2bf(c2[m][r]);
      Hs[e * 72 + F + n16] = hv;
      int gn = n0 + e;
      if (layer < LAYERS - 1 && gn < N_NODES)
        hnext[(size_t)gn * 64 + F + n16] = hv;
    }
  __syncthreads();

  if (layer < LAYERS - 1) {
    int lp = layer + 1;
    bf16x8 B3[2][2];
    float w0[2], w1[2], w2[2], bb[2]; bool isU[2];
#pragma unroll
    for (int nt = 0; nt < 2; ++nt) {
      int col = wvi * 32 + nt * 16 + n16;
      const u16* p = W1abT + (size_t)(lp * 128 + col) * 64 + quad * 8;
      B3[nt][0] = __builtin_bit_cast(bf16x8, *(const u16x8*)(p));
      B3[nt][1] = __builtin_bit_cast(bf16x8, *(const u16x8*)(p + 32));
      int f = col & 63; isU[nt] = col >= 64;
      w0[nt] = Wvx[(lp * 3 + 0) * 64 + f];
      w1[nt] = Wvx[(lp * 3 + 1) * 64 + f];
      w2[nt] = Wvx[(lp * 3 + 2) * 64 + f];
      bb[nt] = b1x[lp * 64 + f];
    }
    f32x4 a3[2][2];
#pragma unroll
    for (int m = 0; m < 2; ++m)
#pragma unroll
      for (int nt = 0; nt < 2; ++nt) a3[m][nt] = (f32x4){0.f, 0.f, 0.f, 0.f};
#pragma unroll
    for (int m = 0; m < 2; ++m) {
      const u16* hp = Hs + (m * 16 + n16) * 72 + quad * 8;
      bf16x8 a0 = __builtin_bit_cast(bf16x8, *(const u16x8*)(hp));
      bf16x8 a1 = __builtin_bit_cast(bf16x8, *(const u16x8*)(hp + 32));
#pragma unroll
      for (int nt = 0; nt < 2; ++nt) {
        a3[m][nt] = __builtin_amdgcn_mfma_f32_16x16x32_bf16(a0, B3[nt][0], a3[m][nt], 0, 0, 0);
        a3[m][nt] = __builtin_amdgcn_mfma_f32_16x16x32_bf16(a1, B3[nt][1], a3[m][nt], 0, 0, 0);
      }
    }
#pragma unroll
    for (int m = 0; m < 2; ++m)
#pragma unroll
      for (int nt = 0; nt < 2; ++nt) {
        int col = wvi * 32 + nt * 16 + n16;
        int f = col & 63;
#pragma unroll
        for (int r = 0; r < 4; ++r) {
          int e = m * 16 + quad * 4 + r;
          int grow = n0 + e;
          if (grow < N_NODES) {
            float P = sPos[e * 3] * w0[nt] + sPos[e * 3 + 1] * w1[nt] + sPos[e * 3 + 2] * w2[nt];
            if (!isU[nt]) Sw[(size_t)grow * 64 + f] = f2h(a3[m][nt][r] - P);
            else          Uw[(size_t)grow * 64 + f] = f2h(a3[m][nt][r] + P + bb[nt]);
          }
        }
      }
  } else {
    // fused decoder: out = h2 @ dec_w + dec_b
    int e = t >> 3, part = t & 7;
    float s = 0.f;
#pragma unroll
    for (int j = 0; j < 8; ++j)
      s += bf2f(Hs[e * 72 + part * 8 + j]) * dec_w[part * 8 + j];
    sRed[e][part] = s;
    __syncthreads();
    if (part == 0) {
      int gn = n0 + e;
      if (gn < N_NODES) {
        float acc8 = dec_b[0];
#pragma unroll
        for (int p2 = 0; p2 < 8; ++p2) acc8 += sRed[e][p2];
        out[gn] = acc8;
      }
    }
  }
}

extern "C" void kernel_launch(void* const* d_in, const int* in_sizes, int n_in,
                              void* d_out, int out_size, void* d_ws, size_t ws_size,
                              hipStream_t stream) {
  const float* node_pos   = (const float*)d_in[0];
  const float* node_feat  = (const float*)d_in[1];
  const int*   edge_index = (const int*)d_in[2];
  const float* enc_w      = (const float*)d_in[3];
  const float* enc_b      = (const float*)d_in[4];
  const float* edge_enc_w = (const float*)d_in[5];
  const float* edge_enc_b = (const float*)d_in[6];
  const float* ew1        = (const float*)d_in[7];
  const float* eb1        = (const float*)d_in[8];
  const float* ew2        = (const float*)d_in[9];
  const float* eb2        = (const float*)d_in[10];
  const float* nw1        = (const float*)d_in[11];
  const float* nb1        = (const float*)d_in[12];
  const float* nw2        = (const float*)d_in[13];
  const float* nb2        = (const float*)d_in[14];
  const float* dec_w      = (const float*)d_in[15];
  const float* dec_b      = (const float*)d_in[16];
  float* out = (float*)d_out;

  char* ws = (char*)d_ws;
  size_t off = 0;
  u16*    hA    = (u16*)(ws + off);    off += (size_t)N_NODES * 64 * 2;
  u16*    hB    = (u16*)(ws + off);    off += (size_t)N_NODES * 64 * 2;
  u16*    S0    = (u16*)(ws + off);    off += (size_t)N_NODES * 64 * 2;
  u16*    U0    = (u16*)(ws + off);    off += (size_t)N_NODES * 64 * 2;
  u16*    S1    = (u16*)(ws + off);    off += (size_t)N_NODES * 64 * 2;
  u16*    U1    = (u16*)(ws + off);    off += (size_t)N_NODES * 64 * 2;
  u16*    W1abT = (u16*)(ws + off);    off += (size_t)LAYERS * 128 * 64 * 2;
  float*  Wvx   = (float*)(ws + off);  off += (size_t)LAYERS * 3 * 64 * 4;
  float*  b1x   = (float*)(ws + off);  off += (size_t)LAYERS * 64 * 4;
  u16*    NB1T  = (u16*)(ws + off);    off += (size_t)LAYERS * 64 * 128 * 2;
  float*  bb2   = (float*)(ws + off);  off += (size_t)LAYERS * 64 * 4;
  u16*    M2T   = (u16*)(ws + off);    off += (size_t)LAYERS * 64 * 64 * 2;
  int*    cnt      = (int*)(ws + off); off += (size_t)N_NODES * 4;
  int*    offsB    = (int*)(ws + off); off += (size_t)N_NODES * 4;
  int*    partials = (int*)(ws + off); off += 32 * 4;
  int*    rank     = (int*)(ws + off); off += (size_t)N_EDGES * 4;
  int*    srcB     = (int*)(ws + off); off += (size_t)N_EDGES * 4;

  const int* dstA = edge_index + N_EDGES;
  const int NBLK64 = (N_NODES + 63) / 64;          // 782
  const int NBLK32 = (N_NODES + 31) / 32;          // 1563

  init_kernel<<<512, 256, 0, stream>>>(
      ew1, eb1, ew2, eb2, nw1, nw2, edge_enc_w, edge_enc_b,
      W1abT, Wvx, b1x, NB1T, bb2, M2T, cnt);

  hist_kernel<<<(N_EDGES + 255) / 256, 256, 0, stream>>>(dstA, cnt, rank);
  scan1_kernel<<<SCAN_NBLK, 256, 0, stream>>>(cnt, offsB, partials);
  scan3_kernel<<<(N_NODES + 255) / 256, 256, 0, stream>>>(offsB, partials);
  scatter_kernel<<<(N_EDGES + 255) / 256, 256, 0, stream>>>(edge_index, offsB, rank, srcB);

  encsu_kernel<<<NBLK64, 256, 0, stream>>>(node_feat, enc_w, enc_b,
                                           W1abT, Wvx, b1x, node_pos, hA, S0, U0);

  u16 *hc = hA, *hn = hB, *Sr = S0, *Ur = U0, *Sw = S1, *Uw = U1;
  for (int l = 0; l < LAYERS; ++l) {
    layer_kernel<<<NBLK32, 256, 0, stream>>>(hc, srcB, offsB, Sr, Ur,
                                             NB1T, nb1, bb2, M2T, nb2,
                                             hn, l, W1abT, Wvx, b1x, node_pos,
                                             Sw, Uw, dec_w, dec_b, out);
    u16* tmp;
    tmp = hc; hc = hn; hn = tmp;
    tmp = Sr; Sr = Sw; Sw = tmp;
    tmp = Ur; Ur = Uw; Uw = tmp;
  }
}

// Round 6
// 300.738 us; speedup vs baseline: 1.3342x; 1.0373x over previous
//
#include <hip/hip_runtime.h>

#define N_NODES 50000
#define N_EDGES 800000
#define HID 64
#define LAYERS 4
#define EP_CAP 2048        // staged srcS capacity per 32-node tile (avg ~512)
#define SCAN_NBLK 25
#define NBLK64 782
#define NBLK32 1563

typedef unsigned short u16;
typedef __attribute__((ext_vector_type(8))) __bf16 bf16x8;
typedef __attribute__((ext_vector_type(8))) unsigned short u16x8;
typedef __attribute__((ext_vector_type(4))) float f32x4;
typedef _Float16 f16x2 __attribute__((ext_vector_type(2)));

__device__ __forceinline__ u16 f2bf(float f) {
  unsigned u = __builtin_bit_cast(unsigned, f);
  u += 0x7fffu + ((u >> 16) & 1u);   // RNE
  return (u16)(u >> 16);
}
__device__ __forceinline__ float bf2f(u16 s) {
  return __builtin_bit_cast(float, ((unsigned)s) << 16);
}
__device__ __forceinline__ u16 f2h(float f) {
  return __builtin_bit_cast(u16, (_Float16)f);
}
__device__ __forceinline__ unsigned pkadd(unsigned a, unsigned b) {
  f16x2 r = __builtin_bit_cast(f16x2, a) + __builtin_bit_cast(f16x2, b);
  return __builtin_bit_cast(unsigned, r);
}
__device__ __forceinline__ unsigned pkmax0(unsigned x) {
  unsigned r, z = 0u;
  asm("v_pk_max_f16 %0, %1, %2" : "=v"(r) : "v"(x), "v"(z));
  return r;
}

// ---------------- prep: weight prep + encoder h + hist/rank (one launch) -----
// (cnt must be zeroed by the preceding memset)
// W1abT: [L][128][64] bf16 — cols 0-63 = W1a (src), 64-127 = W1b (dst), [n][k]
// Wvx:   [L][3][64] f32  (We@W1c folded rank-3 edge_vec term)
// b1x:   [L][64] f32     (b1 + be@W1c)
// NB1T:  [L][64][128] bf16 — node GEMM1 B: k<64 = M1a^T, k>=64 = (W2@M1b)^T
// bb2:   [L][64] f32     (b2@M1b — scaled by deg in node epilogue)
// M2T:   [L][64][64] bf16
__global__ __launch_bounds__(256) void prep_kernel(
    const float* __restrict__ nf, const float* __restrict__ enc_w,
    const float* __restrict__ enc_b,
    const float* __restrict__ ew1, const float* __restrict__ eb1,
    const float* __restrict__ ew2, const float* __restrict__ eb2,
    const float* __restrict__ nw1, const float* __restrict__ nw2,
    const float* __restrict__ edge_enc_w, const float* __restrict__ edge_enc_b,
    const int* __restrict__ dstA,
    u16* __restrict__ h, u16* W1abT, float* Wvx, float* b1x,
    u16* NB1T, float* bb2, u16* M2T,
    int* __restrict__ cnt, int* __restrict__ rank) {
  const int T = gridDim.x * 256;
  int tid = blockIdx.x * 256 + threadIdx.x;
  // ---- weights ----
  {
    const int szA = LAYERS * 128 * 64, szV = LAYERS * 3 * 64, szB = LAYERS * 64;
    const int szN = LAYERS * 64 * 128, szb2 = LAYERS * 64, szM = LAYERS * 64 * 64;
    const int tot = szA + szV + szB + szN + szb2 + szM;
    for (int i = tid; i < tot; i += T) {
      int idx = i;
      if (idx < szA) {
        int l = idx / (128 * 64); int r = idx % (128 * 64);
        int nfc = r / 64; int k = r % 64;
        int half = nfc >> 6, f = nfc & 63;
        W1abT[idx] = f2bf(ew1[(l * 192 + half * 64 + k) * 64 + f]);
        continue;
      }
      idx -= szA;
      if (idx < szV) {
        int l = idx / 192, r = idx % 192, a = r / 64, f = r % 64;
        float s = 0.f;
        for (int m = 0; m < 64; ++m) s += edge_enc_w[a * 64 + m] * ew1[(l * 192 + 128 + m) * 64 + f];
        Wvx[idx] = s;
        continue;
      }
      idx -= szV;
      if (idx < szB) {
        int l = idx / 64, f = idx % 64;
        float s = eb1[l * 64 + f];
        for (int m = 0; m < 64; ++m) s += edge_enc_b[m] * ew1[(l * 192 + 128 + m) * 64 + f];
        b1x[idx] = s;
        continue;
      }
      idx -= szB;
      if (idx < szN) {
        int l = idx / 8192, r = idx % 8192, f = r / 128, k = r % 128;
        float v;
        if (k < 64) v = nw1[(l * 128 + k) * 64 + f];
        else {
          int j = k - 64; float s = 0.f;
          for (int g = 0; g < 64; ++g)
            s += ew2[(l * 64 + j) * 64 + g] * nw1[(l * 128 + 64 + g) * 64 + f];
          v = s;
        }
        NB1T[idx] = f2bf(v);
        continue;
      }
      idx -= szN;
      if (idx < szb2) {
        int l = idx / 64, f = idx % 64;
        float s = 0.f;
        for (int g = 0; g < 64; ++g) s += eb2[l * 64 + g] * nw1[(l * 128 + 64 + g) * 64 + f];
        bb2[idx] = s;
        continue;
      }
      idx -= szb2;
      int l = idx / 4096, r = idx % 4096, f = r / 64, k = r % 64;
      M2T[idx] = f2bf(nw2[(l * 64 + k) * 64 + f]);
    }
  }
  // ---- encoder h (8 features / thread, 16B stores) ----
  for (int i = tid; i < N_NODES * 8; i += T) {
    int n = i >> 3, j0 = (i & 7) * 8;
    float x0 = nf[n * 3 + 0], x1 = nf[n * 3 + 1], x2 = nf[n * 3 + 2];
    u16x8 v;
#pragma unroll
    for (int j = 0; j < 8; ++j) {
      int jj = j0 + j;
      float s = enc_b[jj] + x0 * enc_w[jj] + x1 * enc_w[64 + jj] + x2 * enc_w[128 + jj];
      v[j] = f2bf(s);
    }
    *(u16x8*)(h + (size_t)n * 64 + j0) = v;
  }
  // ---- hist + rank ----
  for (int idx = tid; idx < N_EDGES; idx += T)
    rank[idx] = atomicAdd(&cnt[dstA[idx]], 1);
}

// ---------------- scan1: per-2048-block local scan + raw partials ------------
__global__ __launch_bounds__(256) void scan1_kernel(const int* __restrict__ cnt,
                                                    int* __restrict__ offs,
                                                    int* __restrict__ partials) {
  __shared__ int sm[2048];
  __shared__ int ws2[256];
  int t = threadIdx.x, b = blockIdx.x;
  int base = b * 2048;
#pragma unroll
  for (int i = 0; i < 8; ++i) {
    int idx = base + i * 256 + t;
    sm[i * 256 + t] = (idx < N_NODES) ? cnt[idx] : 0;
  }
  __syncthreads();
  int loc[8]; int s = 0;
#pragma unroll
  for (int i = 0; i < 8; ++i) { loc[i] = s; s += sm[t * 8 + i]; }
  ws2[t] = s;
  __syncthreads();
  for (int off = 1; off < 256; off <<= 1) {
    int u = (t >= off) ? ws2[t - off] : 0;
    __syncthreads();
    ws2[t] += u;
    __syncthreads();
  }
  int tbase = (t > 0) ? ws2[t - 1] : 0;
  if (t == 255) partials[b] = ws2[255];
#pragma unroll
  for (int i = 0; i < 8; ++i) {
    int idx = base + t * 8 + i;
    if (idx < N_NODES) offs[idx] = tbase + loc[i];
  }
}

// ---------------- fss: su (b<782) + offs finalize + scatter (one launch) -----
// su: S' = h@W1a − pos·Wv ; U' = h@W1b + pos·Wv + b1 (layer 0, f16 storage)
// offs2[idx] = offs[idx] + psum[idx>>11]  (scan3 folded in)
// scatter: srcB[offs[d]+psum[d>>11]+rank[e]] = src<<7  (atomic-free)
__global__ __launch_bounds__(256) void fss_kernel(
    const u16* __restrict__ h, const u16* __restrict__ W1abT,
    const float* __restrict__ Wvx, const float* __restrict__ b1x,
    const float* __restrict__ pos,
    u16* __restrict__ Sarr, u16* __restrict__ Uarr,
    const int* __restrict__ offs, const int* __restrict__ partials,
    const int* __restrict__ ei, const int* __restrict__ rank,
    int* __restrict__ srcB, int* __restrict__ offs2) {
  __shared__ float sPos[192];
  __shared__ int psum[32];
  int t = threadIdx.x, b = blockIdx.x;

  if (b < NBLK64) {
    // ---- su tile (64 nodes) ----
    int lane = t & 63, wvi = t >> 6;
    int n16 = lane & 15, quad = lane >> 4;
    int n0 = b * 64;
    if (t < 192) {
      int idx = n0 * 3 + t;
      sPos[t] = (idx < N_NODES * 3) ? pos[idx] : 0.f;
    }
    __syncthreads();

    bf16x8 B[2][2];
    float w0[2], w1[2], w2[2], bb[2]; bool isU[2];
#pragma unroll
    for (int nt = 0; nt < 2; ++nt) {
      int col = wvi * 32 + nt * 16 + n16;
      const u16* p = W1abT + (size_t)col * 64 + quad * 8;   // layer 0
      B[nt][0] = __builtin_bit_cast(bf16x8, *(const u16x8*)(p));
      B[nt][1] = __builtin_bit_cast(bf16x8, *(const u16x8*)(p + 32));
      int f = col & 63; isU[nt] = col >= 64;
      w0[nt] = Wvx[f];
      w1[nt] = Wvx[64 + f];
      w2[nt] = Wvx[128 + f];
      bb[nt] = b1x[f];
    }
    f32x4 acc[4][2];
#pragma unroll
    for (int m = 0; m < 4; ++m)
#pragma unroll
      for (int nt = 0; nt < 2; ++nt) acc[m][nt] = (f32x4){0.f, 0.f, 0.f, 0.f};
#pragma unroll
    for (int m = 0; m < 4; ++m) {
      int row = n0 + m * 16 + n16;
      if (row >= N_NODES) row = N_NODES - 1;
      const u16* hp = h + (size_t)row * 64 + quad * 8;
      bf16x8 a0 = __builtin_bit_cast(bf16x8, *(const u16x8*)(hp));
      bf16x8 a1 = __builtin_bit_cast(bf16x8, *(const u16x8*)(hp + 32));
#pragma unroll
      for (int nt = 0; nt < 2; ++nt) {
        acc[m][nt] = __builtin_amdgcn_mfma_f32_16x16x32_bf16(a0, B[nt][0], acc[m][nt], 0, 0, 0);
        acc[m][nt] = __builtin_amdgcn_mfma_f32_16x16x32_bf16(a1, B[nt][1], acc[m][nt], 0, 0, 0);
      }
    }
#pragma unroll
    for (int m = 0; m < 4; ++m)
#pragma unroll
      for (int nt = 0; nt < 2; ++nt) {
        int col = wvi * 32 + nt * 16 + n16;
        int f = col & 63;
#pragma unroll
        for (int r = 0; r < 4; ++r) {
          int e = m * 16 + quad * 4 + r;
          int grow = n0 + e;
          if (grow < N_NODES) {
            float P = sPos[e * 3] * w0[nt] + sPos[e * 3 + 1] * w1[nt] + sPos[e * 3 + 2] * w2[nt];
            if (!isU[nt]) Sarr[(size_t)grow * 64 + f] = f2h(acc[m][nt][r] - P);
            else          Uarr[(size_t)grow * 64 + f] = f2h(acc[m][nt][r] + P + bb[nt]);
          }
        }
      }
  }

  // ---- 25-partial prefix ----
  if (t == 0) {
    int s = 0;
#pragma unroll
    for (int i = 0; i < SCAN_NBLK; ++i) { psum[i] = s; s += partials[i]; }
  }
  __syncthreads();

  int tid = b * 256 + t;
  const int T = gridDim.x * 256;
  // ---- offs finalize ----
  for (int idx = tid; idx < N_NODES; idx += T)
    offs2[idx] = offs[idx] + psum[idx >> 11];
  // ---- scatter (atomic-free; inline-finalized offsets) ----
  for (int idx = tid; idx < N_EDGES; idx += T) {
    int s = ei[idx], d = ei[N_EDGES + idx];
    srcB[offs[d] + psum[d >> 11] + rank[idx]] = s << 7;
  }
}

// ---------------- fused layer: ep (LDS agg) + node MLP, 32-node tiles -------
__global__ __launch_bounds__(256) void layer_kernel(
    const u16* __restrict__ h, const int* __restrict__ srcB,
    const int* __restrict__ offs,
    const u16* __restrict__ Sr, const u16* __restrict__ Ur,
    const u16* __restrict__ NB1T, const float* __restrict__ nb1,
    const float* __restrict__ bb2,
    const u16* __restrict__ M2T, const float* __restrict__ nb2,
    u16* __restrict__ hnext, int layer,
    const u16* __restrict__ W1abT, const float* __restrict__ Wvx,
    const float* __restrict__ b1x, const float* __restrict__ pos,
    u16* __restrict__ Sw, u16* __restrict__ Uw,
    const float* __restrict__ dec_w, const float* __restrict__ dec_b,
    float* __restrict__ out) {
  __shared__ int sIdx[EP_CAP];
  __shared__ int sOff[33];
  __shared__ u16 aggT[32 * 72];
  __shared__ u16 Hs[32 * 72];
  __shared__ float sPos[96];
  __shared__ float sRed[32][8];
  int t = threadIdx.x;
  int lane = t & 63, wvi = t >> 6;
  int n16 = lane & 15, quad = lane >> 4;
  int F = wvi * 16;
  int n0 = blockIdx.x * 32;

  if (t <= 32) {
    int d = n0 + t;
    sOff[t] = (d < N_NODES) ? offs[d] : N_EDGES;
  }
  if (t >= 64 && t < 160) {
    int i = t - 64;
    int idx = n0 * 3 + i;
    sPos[i] = (idx < N_NODES * 3) ? pos[idx] : 0.f;
  }
  __syncthreads();
  int eS = sOff[0];
  int nE = sOff[32] - eS;
  bool fit = (nE <= EP_CAP);
  if (fit) {
    for (int i = t; i < nE; i += 256) sIdx[i] = srcB[eS + i];
    if (t == 0 && nE < EP_CAP) sIdx[nE] = 0;   // safe pad for deg-0 nodes
  }
  __syncthreads();

  // ==== ep phase ====
  {
    int c = lane & 31, half = lane >> 5;
    unsigned cbu = (unsigned)(c << 2);
    const char* __restrict__ Sb = (const char*)Sr;
    const char* __restrict__ Ub = (const char*)Ur;
    for (int i = 0; i < 8; i += 2) {
      int lnA = wvi * 8 + i;
      int dA = n0 + lnA;
      int e0A = sOff[lnA], degA = sOff[lnA + 1] - e0A;
      int e0B = sOff[lnA + 1], degB = sOff[lnA + 2] - e0B;
      int dAc = dA < N_NODES ? dA : N_NODES - 1;
      int dBc = (dA + 1) < N_NODES ? (dA + 1) : N_NODES - 1;
      unsigned upA = *(const unsigned*)(Ub + (size_t)dAc * 128 + cbu);
      unsigned upB = *(const unsigned*)(Ub + (size_t)dBc * 128 + cbu);
      float saA = 0.f, sbA = 0.f, saB = 0.f, sbB = 0.f;
      int relA = (degA > 0) ? (e0A - eS) : 0;
      int relB = (degB > 0) ? (e0B - eS) : 0;
      int g0A = (degA > 0) ? e0A : 0;
      int g0B = (degB > 0) ? e0B : 0;
      int degMin = degA < degB ? degA : degB;
      int degMax = degA > degB ? degA : degB;
      int fullr = degMin >> 4;
      int rmax = (degMax + 15) >> 4;
      if (fit) {
        int r = 0;
        for (; r < fullr; ++r) {             // mask-free
          int base = r * 16 + half;
          unsigned wA[8], wB[8];
#pragma unroll
          for (int kk = 0; kk < 8; ++kk) {
            int j = base + 2 * kk;
            wA[kk] = *(const unsigned*)(Sb + (unsigned)sIdx[relA + j] + cbu);
            wB[kk] = *(const unsigned*)(Sb + (unsigned)sIdx[relB + j] + cbu);
          }
          unsigned pA = 0u, pB = 0u;
#pragma unroll
          for (int kk = 0; kk < 8; ++kk) {
            pA = pkadd(pA, pkmax0(pkadd(wA[kk], upA)));
            pB = pkadd(pB, pkmax0(pkadd(wB[kk], upB)));
          }
          f16x2 hA2 = __builtin_bit_cast(f16x2, pA);
          f16x2 hB2 = __builtin_bit_cast(f16x2, pB);
          saA += (float)hA2[0]; sbA += (float)hA2[1];
          saB += (float)hB2[0]; sbB += (float)hB2[1];
        }
        for (; r < rmax; ++r) {              // masked remainder
          int base = r * 16 + half;
          unsigned wA[8], wB[8]; bool okA[8], okB[8];
#pragma unroll
          for (int kk = 0; kk < 8; ++kk) {
            int j = base + 2 * kk;
            okA[kk] = j < degA;
            wA[kk] = *(const unsigned*)(Sb + (unsigned)sIdx[relA + (okA[kk] ? j : 0)] + cbu);
            okB[kk] = j < degB;
            wB[kk] = *(const unsigned*)(Sb + (unsigned)sIdx[relB + (okB[kk] ? j : 0)] + cbu);
          }
          unsigned pA = 0u, pB = 0u;
#pragma unroll
          for (int kk = 0; kk < 8; ++kk) {
            unsigned zA = pkmax0(pkadd(wA[kk], upA));
            pA = pkadd(pA, okA[kk] ? zA : 0u);
            unsigned zB = pkmax0(pkadd(wB[kk], upB));
            pB = pkadd(pB, okB[kk] ? zB : 0u);
          }
          f16x2 hA2 = __builtin_bit_cast(f16x2, pA);
          f16x2 hB2 = __builtin_bit_cast(f16x2, pB);
          saA += (float)hA2[0]; sbA += (float)hA2[1];
          saB += (float)hB2[0]; sbB += (float)hB2[1];
        }
      } else {                                // overflow fallback
        for (int r = 0; r < rmax; ++r) {
          int base = r * 16 + half;
          unsigned wA[8], wB[8]; bool okA[8], okB[8];
#pragma unroll
          for (int kk = 0; kk < 8; ++kk) {
            int j = base + 2 * kk;
            okA[kk] = j < degA;
            wA[kk] = *(const unsigned*)(Sb + (unsigned)srcB[g0A + (okA[kk] ? j : 0)] + cbu);
            okB[kk] = j < degB;
            wB[kk] = *(const unsigned*)(Sb + (unsigned)srcB[g0B + (okB[kk] ? j : 0)] + cbu);
          }
          unsigned pA = 0u, pB = 0u;
#pragma unroll
          for (int kk = 0; kk < 8; ++kk) {
            unsigned zA = pkmax0(pkadd(wA[kk], upA));
            pA = pkadd(pA, okA[kk] ? zA : 0u);
            unsigned zB = pkmax0(pkadd(wB[kk], upB));
            pB = pkadd(pB, okB[kk] ? zB : 0u);
          }
          f16x2 hA2 = __builtin_bit_cast(f16x2, pA);
          f16x2 hB2 = __builtin_bit_cast(f16x2, pB);
          saA += (float)hA2[0]; sbA += (float)hA2[1];
          saB += (float)hB2[0]; sbB += (float)hB2[1];
        }
      }
      saA += __shfl_xor(saA, 32);  sbA += __shfl_xor(sbA, 32);
      saB += __shfl_xor(saB, 32);  sbB += __shfl_xor(sbB, 32);
      if (half == 0) {
        unsigned pk = (unsigned)f2bf(saA) | ((unsigned)f2bf(sbA) << 16);
        *(unsigned*)((char*)aggT + (size_t)lnA * 144 + cbu) = pk;
        unsigned pk2 = (unsigned)f2bf(saB) | ((unsigned)f2bf(sbB) << 16);
        *(unsigned*)((char*)aggT + (size_t)(lnA + 1) * 144 + cbu) = pk2;
      }
    }
  }
  __syncthreads();

  // ==== node MLP ====
  bf16x8 B1[4], B2[2];
  {
    const u16* p = NB1T + (size_t)(layer * 64 + F + n16) * 128 + quad * 8;
#pragma unroll
    for (int ks = 0; ks < 4; ++ks) B1[ks] = __builtin_bit_cast(bf16x8, *(const u16x8*)(p + ks * 32));
    const u16* q = M2T + (size_t)(layer * 64 + F + n16) * 64 + quad * 8;
#pragma unroll
    for (int ks = 0; ks < 2; ++ks) B2[ks] = __builtin_bit_cast(bf16x8, *(const u16x8*)(q + ks * 32));
  }
  float bias1 = nb1[layer * 64 + F + n16];
  float bb2f = bb2[layer * 64 + F + n16];
  float bias2 = nb2[layer * 64 + F + n16];

  // GEMM1: [h | aggT] @ NB1T (32 rows)
  f32x4 acc[2];
#pragma unroll
  for (int m = 0; m < 2; ++m) acc[m] = (f32x4){0.f, 0.f, 0.f, 0.f};
#pragma unroll
  for (int m = 0; m < 2; ++m) {
    int row = n0 + m * 16 + n16;
    if (row >= N_NODES) row = N_NODES - 1;
    const u16* hp = h + (size_t)row * 64 + quad * 8;
    const u16* ap = aggT + (m * 16 + n16) * 72 + quad * 8;
    bf16x8 a0 = __builtin_bit_cast(bf16x8, *(const u16x8*)(hp));
    bf16x8 a1 = __builtin_bit_cast(bf16x8, *(const u16x8*)(hp + 32));
    bf16x8 a2 = __builtin_bit_cast(bf16x8, *(const u16x8*)(ap));
    bf16x8 a3 = __builtin_bit_cast(bf16x8, *(const u16x8*)(ap + 32));
    acc[m] = __builtin_amdgcn_mfma_f32_16x16x32_bf16(a0, B1[0], acc[m], 0, 0, 0);
    acc[m] = __builtin_amdgcn_mfma_f32_16x16x32_bf16(a1, B1[1], acc[m], 0, 0, 0);
    acc[m] = __builtin_amdgcn_mfma_f32_16x16x32_bf16(a2, B1[2], acc[m], 0, 0, 0);
    acc[m] = __builtin_amdgcn_mfma_f32_16x16x32_bf16(a3, B1[3], acc[m], 0, 0, 0);
  }
#pragma unroll
  for (int m = 0; m < 2; ++m)
#pragma unroll
    for (int r = 0; r < 4; ++r) {
      int e = m * 16 + quad * 4 + r;
      float dg = (float)(sOff[e + 1] - sOff[e]);
      float v = acc[m][r] + bias1 + dg * bb2f;
      v = v > 0.f ? v : 0.f;
      Hs[e * 72 + F + n16] = f2bf(v);
    }
  __syncthreads();

  // GEMM2: hidden @ M2T -> h2 (registers)
  float c2[2][4];
#pragma unroll
  for (int m = 0; m < 2; ++m) {
    const u16* hp = Hs + (m * 16 + n16) * 72 + quad * 8;
    f32x4 cc = (f32x4){0.f, 0.f, 0.f, 0.f};
#pragma unroll
    for (int ks = 0; ks < 2; ++ks) {
      bf16x8 a = __builtin_bit_cast(bf16x8, *(const u16x8*)(hp + ks * 32));
      cc = __builtin_amdgcn_mfma_f32_16x16x32_bf16(a, B2[ks], cc, 0, 0, 0);
    }
#pragma unroll
    for (int r = 0; r < 4; ++r) c2[m][r] = cc[r] + bias2;
  }
  __syncthreads();   // all Hs reads done

  // h2 -> LDS (+ global if another layer follows)
#pragma unroll
  for (int m = 0; m < 2; ++m)
#pragma unroll
    for (int r = 0; r < 4; ++r) {
      int e = m * 16 + quad * 4 + r;
      u16 hv = f2bf(c2[m][r]);
      Hs[e * 72 + F + n16] = hv;
      int gn = n0 + e;
      if (layer < LAYERS - 1 && gn < N_NODES)
        hnext[(size_t)gn * 64 + F + n16] = hv;
    }
  __syncthreads();

  if (layer < LAYERS - 1) {
    int lp = layer + 1;
    bf16x8 B3[2][2];
    float w0[2], w1[2], w2[2], bb[2]; bool isU[2];
#pragma unroll
    for (int nt = 0; nt < 2; ++nt) {
      int col = wvi * 32 + nt * 16 + n16;
      const u16* p = W1abT + (size_t)(lp * 128 + col) * 64 + quad * 8;
      B3[nt][0] = __builtin_bit_cast(bf16x8, *(const u16x8*)(p));
      B3[nt][1] = __builtin_bit_cast(bf16x8, *(const u16x8*)(p + 32));
      int f = col & 63; isU[nt] = col >= 64;
      w0[nt] = Wvx[(lp * 3 + 0) * 64 + f];
      w1[nt] = Wvx[(lp * 3 + 1) * 64 + f];
      w2[nt] = Wvx[(lp * 3 + 2) * 64 + f];
      bb[nt] = b1x[lp * 64 + f];
    }
    f32x4 a3[2][2];
#pragma unroll
    for (int m = 0; m < 2; ++m)
#pragma unroll
      for (int nt = 0; nt < 2; ++nt) a3[m][nt] = (f32x4){0.f, 0.f, 0.f, 0.f};
#pragma unroll
    for (int m = 0; m < 2; ++m) {
      const u16* hp = Hs + (m * 16 + n16) * 72 + quad * 8;
      bf16x8 a0 = __builtin_bit_cast(bf16x8, *(const u16x8*)(hp));
      bf16x8 a1 = __builtin_bit_cast(bf16x8, *(const u16x8*)(hp + 32));
#pragma unroll
      for (int nt = 0; nt < 2; ++nt) {
        a3[m][nt] = __builtin_amdgcn_mfma_f32_16x16x32_bf16(a0, B3[nt][0], a3[m][nt], 0, 0, 0);
        a3[m][nt] = __builtin_amdgcn_mfma_f32_16x16x32_bf16(a1, B3[nt][1], a3[m][nt], 0, 0, 0);
      }
    }
#pragma unroll
    for (int m = 0; m < 2; ++m)
#pragma unroll
      for (int nt = 0; nt < 2; ++nt) {
        int col = wvi * 32 + nt * 16 + n16;
        int f = col & 63;
#pragma unroll
        for (int r = 0; r < 4; ++r) {
          int e = m * 16 + quad * 4 + r;
          int grow = n0 + e;
          if (grow < N_NODES) {
            float P = sPos[e * 3] * w0[nt] + sPos[e * 3 + 1] * w1[nt] + sPos[e * 3 + 2] * w2[nt];
            if (!isU[nt]) Sw[(size_t)grow * 64 + f] = f2h(a3[m][nt][r] - P);
            else          Uw[(size_t)grow * 64 + f] = f2h(a3[m][nt][r] + P + bb[nt]);
          }
        }
      }
  } else {
    // fused decoder: out = h2 @ dec_w + dec_b
    int e = t >> 3, part = t & 7;
    float s = 0.f;
#pragma unroll
    for (int j = 0; j < 8; ++j)
      s += bf2f(Hs[e * 72 + part * 8 + j]) * dec_w[part * 8 + j];
    sRed[e][part] = s;
    __syncthreads();
    if (part == 0) {
      int gn = n0 + e;
      if (gn < N_NODES) {
        float acc8 = dec_b[0];
#pragma unroll
        for (int p2 = 0; p2 < 8; ++p2) acc8 += sRed[e][p2];
        out[gn] = acc8;
      }
    }
  }
}

extern "C" void kernel_launch(void* const* d_in, const int* in_sizes, int n_in,
                              void* d_out, int out_size, void* d_ws, size_t ws_size,
                              hipStream_t stream) {
  const float* node_pos   = (const float*)d_in[0];
  const float* node_feat  = (const float*)d_in[1];
  const int*   edge_index = (const int*)d_in[2];
  const float* enc_w      = (const float*)d_in[3];
  const float* enc_b      = (const float*)d_in[4];
  const float* edge_enc_w = (const float*)d_in[5];
  const float* edge_enc_b = (const float*)d_in[6];
  const float* ew1        = (const float*)d_in[7];
  const float* eb1        = (const float*)d_in[8];
  const float* ew2        = (const float*)d_in[9];
  const float* eb2        = (const float*)d_in[10];
  const float* nw1        = (const float*)d_in[11];
  const float* nb1        = (const float*)d_in[12];
  const float* nw2        = (const float*)d_in[13];
  const float* nb2        = (const float*)d_in[14];
  const float* dec_w      = (const float*)d_in[15];
  const float* dec_b      = (const float*)d_in[16];
  float* out = (float*)d_out;

  char* ws = (char*)d_ws;
  size_t off = 0;
  u16*    hA    = (u16*)(ws + off);    off += (size_t)N_NODES * 64 * 2;
  u16*    hB    = (u16*)(ws + off);    off += (size_t)N_NODES * 64 * 2;
  u16*    S0    = (u16*)(ws + off);    off += (size_t)N_NODES * 64 * 2;
  u16*    U0    = (u16*)(ws + off);    off += (size_t)N_NODES * 64 * 2;
  u16*    S1    = (u16*)(ws + off);    off += (size_t)N_NODES * 64 * 2;
  u16*    U1    = (u16*)(ws + off);    off += (size_t)N_NODES * 64 * 2;
  u16*    W1abT = (u16*)(ws + off);    off += (size_t)LAYERS * 128 * 64 * 2;
  float*  Wvx   = (float*)(ws + off);  off += (size_t)LAYERS * 3 * 64 * 4;
  float*  b1x   = (float*)(ws + off);  off += (size_t)LAYERS * 64 * 4;
  u16*    NB1T  = (u16*)(ws + off);    off += (size_t)LAYERS * 64 * 128 * 2;
  float*  bb2   = (float*)(ws + off);  off += (size_t)LAYERS * 64 * 4;
  u16*    M2T   = (u16*)(ws + off);    off += (size_t)LAYERS * 64 * 64 * 2;
  int*    cnt      = (int*)(ws + off); off += (size_t)N_NODES * 4;
  int*    offsA    = (int*)(ws + off); off += (size_t)N_NODES * 4;  // raw scan
  int*    offsB    = (int*)(ws + off); off += (size_t)N_NODES * 4;  // finalized
  int*    partials = (int*)(ws + off); off += 32 * 4;
  int*    rank     = (int*)(ws + off); off += (size_t)N_EDGES * 4;
  int*    srcB     = (int*)(ws + off); off += (size_t)N_EDGES * 4;

  const int* dstA = edge_index + N_EDGES;

  hipMemsetAsync(cnt, 0, (size_t)N_NODES * 4, stream);

  prep_kernel<<<3125, 256, 0, stream>>>(
      node_feat, enc_w, enc_b, ew1, eb1, ew2, eb2, nw1, nw2,
      edge_enc_w, edge_enc_b, dstA,
      hA, W1abT, Wvx, b1x, NB1T, bb2, M2T, cnt, rank);

  scan1_kernel<<<SCAN_NBLK, 256, 0, stream>>>(cnt, offsA, partials);

  fss_kernel<<<NBLK32, 256, 0, stream>>>(
      hA, W1abT, Wvx, b1x, node_pos, S0, U0,
      offsA, partials, edge_index, rank, srcB, offsB);

  u16 *hc = hA, *hn = hB, *Sr = S0, *Ur = U0, *Sw = S1, *Uw = U1;
  for (int l = 0; l < LAYERS; ++l) {
    layer_kernel<<<NBLK32, 256, 0, stream>>>(hc, srcB, offsB, Sr, Ur,
                                             NB1T, nb1, bb2, M2T, nb2,
                                             hn, l, W1abT, Wvx, b1x, node_pos,
                                             Sw, Uw, dec_w, dec_b, out);
    u16* tmp;
    tmp = hc; hc = hn; hn = tmp;
    tmp = Sr; Sr = Sw; Sw = tmp;
    tmp = Ur; Ur = Uw; Uw = tmp;
  }
}